// Round 9
// baseline (1502.584 us; speedup 1.0000x reference)
//
#include <hip/hip_runtime.h>
#include <cstdint>
#include <cmath>

#define HW 64
#define NPIX 4096          // 64*64
#define CIN 512
#define NANCH 36864        // 4096*9
#define PREN 3000
#define POSTN 300
#define ICL 8
#define NSL 9              // ceil(8*4*68 / 256); last slot: t < 128

// ------ W reshape: w[oc][ic][3][3] -> w4[g][ic][h][tap][o4] ---------------
// g = oct*4 + wid (64 groups of 8 oc), oc = (g>>2)*32 + (g&3)*8 + h*4 + o4
__global__ __launch_bounds__(256) void reshape_w_kernel(
    const float* __restrict__ w, float* __restrict__ w4) {
  int gid = blockIdx.x * 256 + threadIdx.x;
  if (gid >= 512 * 512 * 9) return;
  int o4  = gid & 3;
  int r   = gid >> 2;          // ((g*512+ic)*2+h)*9 + tap
  int tap = r % 9;
  int r2  = r / 9;             // (g*512+ic)*2 + h
  int h   = r2 & 1;
  int r3  = r2 >> 1;           // g*512 + ic
  int ic  = r3 & 511;
  int g   = r3 >> 9;
  int oc  = (g >> 2) * 32 + (g & 3) * 8 + h * 4 + o4;
  w4[gid] = w[((size_t)oc * 512 + ic) * 9 + tap];
}

// ---------------- 3x3 conv + bias + ReLU -> feat2 (NHWC) -----------------
// grid (16 oct, 32 ytile, 4 n) = 2048 blocks = 8/CU, 32 waves/CU (100% occ).
// Wave = 8 oc (SGPR ping-pong weight stream). Lane = 2 rows x 2 cols.
// LDS: 2-row output tile -> 4-row window, linear-affine staging writes.
#define WLOAD(DST, UPTR) do {                                                \
    _Pragma("unroll")                                                        \
    for (int q = 0; q < 36; ++q) (DST)[q] = (UPTR)[q];                       \
  } while (0)

#define CONV_HALF4(W, OB) do {                                               \
    _Pragma("unroll")                                                        \
    for (int r = 0; r < 3; ++r)                                              \
    _Pragma("unroll")                                                        \
    for (int kx = 0; kx < 3; ++kx) {                                         \
      _Pragma("unroll")                                                      \
      for (int o = 0; o < 4; ++o) {                                          \
        const float wv = (W)[(r * 3 + kx) * 4 + o];                          \
        _Pragma("unroll")                                                    \
        for (int j = 0; j < 2; ++j)                                          \
          acc[(OB) + o][j] = fmaf(wv, xr[r][j + kx], acc[(OB) + o][j]);      \
      }                                                                      \
    }                                                                        \
  } while (0)

__global__ __launch_bounds__(256, 8) void conv3_kernel(
    const float* __restrict__ x, const float* __restrict__ w4,
    const float* __restrict__ b, float* __restrict__ feat2) {
  const int oct = blockIdx.x;      // 0..15
  const int yt  = blockIdx.y;      // 0..31
  const int n   = blockIdx.z;
  const int t   = threadIdx.x;
  const int wid  = __builtin_amdgcn_readfirstlane(t >> 6);
  const int lane = t & 63;
  const int lrow  = lane >> 5;           // 0..1
  const int lcol2 = (lane & 31) << 1;    // 0..62
  const int y0 = yt << 1;

  __shared__ float xs[2][ICL * 272];     // [buf][icl*272 + row*68 + col]

  float acc[8][2];
#pragma unroll
  for (int o = 0; o < 8; ++o) { acc[o][0] = 0.f; acc[o][1] = 0.f; }

  const float* xb = x + (size_t)n * CIN * NPIX;
  const float* __restrict__ wq = w4 + (size_t)(oct * 4 + wid) * (512 * 72);

  // ---- staging slots: LDS offset o = t + k*256 (affine); tile = 8*4*68 ----
  int goff[NSL];
  unsigned valm = 0;
#pragma unroll
  for (int k = 0; k < NSL; ++k) {
    int o   = t + (k << 8);
    int icl = o / 272;
    int rem = o - icl * 272;
    int row = rem / 68;
    int col = rem - row * 68;         // col: 0=left halo, 1..64 data, 65+ pad
    int yy = y0 - 1 + row;
    int xx = col - 1;
    bool act = (k < NSL - 1) || (t < 128);  // o < 2176
    bool v = act && (col >= 1) && (col <= 64) && (yy >= 0) && (yy < 64);
    if (v) valm |= (1u << k);
    goff[k] = icl * NPIX + yy * 64 + xx;
  }

  { // prologue: chunk 0 -> buf 0
    float v[NSL];
#pragma unroll
    for (int k = 0; k < NSL; ++k) v[k] = ((valm >> k) & 1u) ? xb[goff[k]] : 0.f;
#pragma unroll
    for (int k = 0; k < NSL; ++k)
      if (k < NSL - 1 || t < 128) xs[0][t + (k << 8)] = v[k];
  }

  float wbA[36], wbB[36];
  WLOAD(wbA, wq);                         // unit 0

  for (int cch = 0; cch < 64; ++cch) {
    const int cur = cch & 1;
    float rn[NSL];
    if (cch < 63) {                       // next x chunk issued before barrier
      const float* xn = xb + (size_t)(cch + 1) * (ICL * NPIX);
#pragma unroll
      for (int k = 0; k < NSL; ++k) rn[k] = ((valm >> k) & 1u) ? xn[goff[k]] : 0.f;
    }
    __syncthreads();                      // buf[cur] ready
#pragma unroll 1
    for (int icl = 0; icl < ICL; ++icl) {
      const int u0 = (cch << 4) + (icl << 1);
      const float* xp = &xs[cur][icl * 272 + lrow * 68 + lcol2];
      float2 r0a = *(const float2*)(xp);
      float2 r0b = *(const float2*)(xp + 2);
      float2 r1a = *(const float2*)(xp + 68);
      float2 r1b = *(const float2*)(xp + 70);
      float2 r2a = *(const float2*)(xp + 136);
      float2 r2b = *(const float2*)(xp + 138);
      float xr[3][4] = {{r0a.x, r0a.y, r0b.x, r0b.y},
                        {r1a.x, r1a.y, r1b.x, r1b.y},
                        {r2a.x, r2a.y, r2b.x, r2b.y}};
      WLOAD(wbB, wq + (size_t)(u0 + 1) * 36);    // prefetch half B
      CONV_HALF4(wbA, 0);                        // oc 0..3 (72 FMA)
      {
        const int un = (u0 + 2 < 1024) ? (u0 + 2) : 1023;
        WLOAD(wbA, wq + (size_t)un * 36);        // prefetch next half A
      }
      CONV_HALF4(wbB, 4);                        // oc 4..7 (72 FMA)
    }
    if (cch < 63) {
#pragma unroll
      for (int k = 0; k < NSL; ++k)
        if (k < NSL - 1 || t < 128) xs[cur ^ 1][t + (k << 8)] = rn[k];
    }
  }

  const float* __restrict__ bs = b + oct * 32 + wid * 8;  // uniform
  float bias[8];
#pragma unroll
  for (int o = 0; o < 8; ++o) bias[o] = bs[o];
  const int row = y0 + lrow;
#pragma unroll
  for (int j = 0; j < 2; ++j) {
    const int col = lcol2 + j;
    float* ob = feat2 + ((size_t)n * NPIX + row * 64 + col) * 512 + oct * 32 + wid * 8;
    float4 v0, v1;
    v0.x = fmaxf(acc[0][j] + bias[0], 0.f);
    v0.y = fmaxf(acc[1][j] + bias[1], 0.f);
    v0.z = fmaxf(acc[2][j] + bias[2], 0.f);
    v0.w = fmaxf(acc[3][j] + bias[3], 0.f);
    v1.x = fmaxf(acc[4][j] + bias[4], 0.f);
    v1.y = fmaxf(acc[5][j] + bias[5], 0.f);
    v1.z = fmaxf(acc[6][j] + bias[6], 0.f);
    v1.w = fmaxf(acc[7][j] + bias[7], 0.f);
    *(float4*)(ob)     = v0;
    *(float4*)(ob + 4) = v1;
  }
}

// ---- 1x1 convs + bias -> outputs, FUSED with decode/softmax/keys/hist ----
__global__ __launch_bounds__(256) void conv1_decode_kernel(
    const float* __restrict__ feat2,
    const float* __restrict__ w_loc, const float* __restrict__ b_loc,
    const float* __restrict__ w_score, const float* __restrict__ b_score,
    const int* __restrict__ ih, const int* __restrict__ iw,
    float* __restrict__ out_locs, float* __restrict__ out_scores,
    float* __restrict__ boxes, unsigned* __restrict__ keys,
    unsigned* __restrict__ hist, float* __restrict__ out_anchor) {
#pragma clang fp contract(off)
  const int y = blockIdx.x, n = blockIdx.y;
  const int t = threadIdx.x;
  const int px = t & 63, grp = t >> 6;
  const int lane = t & 63;
  __shared__ float fl[64 * 129];
  __shared__ float wl[54 * 128];           // reused as [px][54] stash after GEMM
  float acc[14];
#pragma unroll
  for (int k = 0; k < 14; ++k) acc[k] = 0.f;
  const float* fb = feat2 + ((size_t)n * NPIX + y * 64) * 512;
  for (int ch = 0; ch < 512; ch += 128) {
    for (int idx = t; idx < 64 * 128; idx += 256) {
      int p = idx >> 7, ic = idx & 127;
      fl[p * 129 + ic] = fb[(size_t)p * 512 + ch + ic];
    }
    for (int idx = t; idx < 54 * 128; idx += 256) {
      int c = idx >> 7, ic = idx & 127;
      wl[c * 128 + ic] = (c < 36) ? w_loc[c * 512 + ch + ic]
                                  : w_score[(c - 36) * 512 + ch + ic];
    }
    __syncthreads();
#pragma unroll 4
    for (int ic = 0; ic < 128; ++ic) {
      float f = fl[px * 129 + ic];
#pragma unroll
      for (int k = 0; k < 14; ++k) {
        int c = grp + 4 * k;
        if (c < 54) acc[k] = fmaf(wl[c * 128 + ic], f, acc[k]);
      }
    }
    __syncthreads();
  }
  size_t pix0 = (size_t)y * 64 + px;
#pragma unroll
  for (int k = 0; k < 14; ++k) {
    int c = grp + 4 * k;
    if (c < 36) {
      float v = acc[k] + b_loc[c];
      out_locs[((size_t)n * NPIX + pix0) * 36 + c] = v;
      wl[px * 54 + c] = v;
    } else if (c < 54) {
      float v = acc[k] + b_score[c - 36];
      out_scores[((size_t)n * NPIX + pix0) * 18 + (c - 36)] = v;
      wl[px * 54 + c] = v;
    }
  }
  __syncthreads();
  // ---- decode: 576 tasks (64 px x 9 anchors) over 256 threads ----
  for (int task = t; task < 576; task += 256) {
    int lpx = task / 9;
    int a   = task - lpx * 9;
    int xq = lpx, yq = y;
    int i = (yq * 64 + xq) * 9 + a;
    int gid = n * NANCH + i;
    int ri = a / 3, si = a - ri * 3;
    double ratio = (ri == 0) ? 0.5 : (ri == 1 ? 1.0 : 2.0);
    double scl   = (si == 0) ? 8.0 : (si == 1 ? 16.0 : 32.0);
    double hh = 16.0 * scl * sqrt(ratio);
    double ww = 16.0 * scl * sqrt(1.0 / ratio);
    float sx = (float)(xq * 16), sy = (float)(yq * 16);
    float ax1 = (float)(8.0 - ww * 0.5) + sx;
    float ay1 = (float)(8.0 - hh * 0.5) + sy;
    float ax2 = (float)(8.0 + ww * 0.5) + sx;
    float ay2 = (float)(8.0 + hh * 0.5) + sy;
    if (n == 0) {
      *(float4*)(out_anchor + (size_t)i * 4) = make_float4(ax1, ay1, ax2, ay2);
    }
    float l0 = wl[lpx * 54 + a * 4 + 0];
    float l1 = wl[lpx * 54 + a * 4 + 1];
    float l2 = wl[lpx * 54 + a * 4 + 2];
    float l3 = wl[lpx * 54 + a * 4 + 3];
    float aw = ax2 - ax1, ah = ay2 - ay1;
    float cx = ax1 + 0.5f * aw, cy = ay1 + 0.5f * ah;
    float ctrx = l0 * aw + cx, ctry = l1 * ah + cy;
    float nw = expf(l2) * aw, nh = expf(l3) * ah;
    float x1 = ctrx - 0.5f * nw, y1 = ctry - 0.5f * nh;
    float x2 = ctrx + 0.5f * nw, y2 = ctry + 0.5f * nh;
    float W = (float)iw[0], H = (float)ih[0];
    x1 = fminf(fmaxf(x1, 0.f), W);
    y1 = fminf(fmaxf(y1, 0.f), H);
    x2 = fminf(fmaxf(x2, 0.f), W);
    y2 = fminf(fmaxf(y2, 0.f), H);
    bool valid = ((x2 - x1) >= 16.f) && ((y2 - y1) >= 16.f);
    float s0 = wl[lpx * 54 + 36 + a * 2];
    float s1 = wl[lpx * 54 + 36 + a * 2 + 1];
    float mx = fmaxf(s0, s1);
    float e0 = expf(s0 - mx), e1 = expf(s1 - mx);
    float fg = e1 / (e0 + e1);
    float sc = valid ? fg : -1e9f;
    unsigned bb = __float_as_uint(sc);
    unsigned v = (bb & 0x80000000u) ? ~bb : (bb | 0x80000000u);  // ascending
    keys[gid] = v;
    *(float4*)(boxes + (size_t)gid * 4) = make_float4(x1, y1, x2, y2);
    unsigned bin = v >> 16;
    unsigned long long mv = __ballot(!valid);   // invalid => one shared bin
    if (!valid) {
      int leader = __ffsll(mv) - 1;
      if (lane == leader)
        atomicAdd(&hist[(size_t)n * 65536 + bin], (unsigned)__popcll(mv));
    } else {
      atomicAdd(&hist[(size_t)n * 65536 + bin], 1u);
    }
  }
}

// ------- find threshold bin P: count(v>>16 >= P) >= PREN, minimal set -----
__global__ __launch_bounds__(256) void scan_kernel(
    const unsigned* __restrict__ hist, unsigned* __restrict__ cut) {
  int n = blockIdx.x;
  int t = threadIdx.x;
  const unsigned* h = hist + (size_t)n * 65536;
  __shared__ unsigned csum[256];
  __shared__ unsigned fine[256];
  __shared__ unsigned csel, cumsh;
  unsigned s = 0;
  for (int bq = 0; bq < 256; ++bq) s += h[t * 256 + bq];
  csum[t] = s;
  __syncthreads();
  if (t == 0) {
    unsigned cum = 0;
    int c = 255;
    for (; c > 0; --c) {
      if (cum + csum[c] >= PREN) break;
      cum += csum[c];
    }
    csel = (unsigned)c;
    cumsh = cum;
  }
  __syncthreads();
  int c = (int)csel;
  fine[t] = h[c * 256 + t];               // parallel, coalesced
  __syncthreads();
  if (t == 0) {
    unsigned cum = cumsh;
    unsigned P = (unsigned)(c * 256);
    for (int bq = 255; bq >= 0; --bq) {
      cum += fine[bq];
      if (cum >= PREN) { P = (unsigned)(c * 256 + bq); break; }
    }
    cut[n] = P;
  }
}

// ---- compact candidates (v>>16 >= P) with wave-aggregated atomics --------
__global__ __launch_bounds__(256) void compact_kernel(
    const unsigned* __restrict__ keys, const unsigned* __restrict__ cut,
    unsigned* __restrict__ cnt, unsigned long long* __restrict__ cand) {
  int gid = blockIdx.x * 256 + threadIdx.x;
  int lane = threadIdx.x & 63;
  int n = gid / NANCH;
  int i = gid - n * NANCH;
  unsigned v = keys[gid];
  bool take = (v >> 16) >= cut[n];
  unsigned long long m = __ballot(take);
  if (take) {
    int leader = __ffsll(m) - 1;
    int tot = __popcll(m);
    int pre = __popcll(m & ((lane == 0) ? 0ull : (~0ull >> (64 - lane))));
    unsigned base = 0;
    if (lane == leader) base = atomicAdd(&cnt[n], (unsigned)tot);
    base = __shfl(base, leader);
    cand[(size_t)n * NANCH + base + pre] =
        ((unsigned long long)v << 32) | (unsigned)(~i);
  }
}

// ---- exact rank among candidates (== global rank) -> score-sorted boxes --
__global__ __launch_bounds__(256) void rank2_kernel(
    const unsigned long long* __restrict__ cand, const unsigned* __restrict__ cnt,
    const float* __restrict__ boxes, float* __restrict__ sboxes) {
  int n = blockIdx.y;
  int C = (int)cnt[n];
  if (blockIdx.x * 256 >= C) return;
  int t = threadIdx.x;
  int i = blockIdx.x * 256 + t;
  const unsigned long long* cb = cand + (size_t)n * NANCH;
  unsigned long long Ki = (i < C) ? cb[i] : 0ull;
  __shared__ unsigned long long tile[256];
  int rank = 0;
  for (int t0 = 0; t0 < C; t0 += 256) {
    __syncthreads();
    int j = t0 + t;
    tile[t] = (j < C) ? cb[j] : 0ull;
    __syncthreads();
#pragma unroll 16
    for (int jj = 0; jj < 256; ++jj)
      rank += (tile[jj] > Ki) ? 1 : 0;
  }
  if (i < C && rank < PREN) {
    unsigned orig = ~(unsigned)(Ki & 0xffffffffull);
    float4 bb = *(const float4*)(boxes + ((size_t)n * NANCH + orig) * 4);
    *(float4*)(sboxes + ((size_t)n * PREN + rank) * 4) = bb;
  }
}

// ------------------ suppression bit-matrix (IoU > 0.7) --------------------
__global__ __launch_bounds__(256) void iou_kernel(
    const float* __restrict__ sboxes, unsigned long long* __restrict__ sup) {
#pragma clang fp contract(off)
  int n = blockIdx.y, i = blockIdx.x;
  const float* B = sboxes + (size_t)n * PREN * 4;
  float4 bi = *(const float4*)(B + (size_t)i * 4);
  float area_i = (bi.z - bi.x) * (bi.w - bi.y);
  int lane = threadIdx.x & 63, wv = threadIdx.x >> 6;
  unsigned long long* row = sup + ((size_t)n * PREN + i) * 64;
  for (int w0 = wv; w0 < 64; w0 += 4) {
    int j = w0 * 64 + lane;
    bool p = false;
    if (j < PREN) {
      float4 bj = *(const float4*)(B + (size_t)j * 4);
      float area_j = (bj.z - bj.x) * (bj.w - bj.y);
      float x1 = fmaxf(bi.x, bj.x), y1 = fmaxf(bi.y, bj.y);
      float x2 = fminf(bi.z, bj.z), y2 = fminf(bi.w, bj.w);
      float inter = fmaxf(x2 - x1, 0.f) * fmaxf(y2 - y1, 0.f);
      float iou = inter / (area_i + area_j - inter + 1e-9f);
      p = iou > 0.7f;
    }
    unsigned long long m = __ballot(p);
    if (lane == 0) row[w0] = m;
  }
}

// -------- word-wise greedy sweep (1 wave/image) + emit 300 rois -----------
__global__ __launch_bounds__(64) void nms_kernel(
    const unsigned long long* __restrict__ sup, const float* __restrict__ sboxes,
    float* __restrict__ rois, float* __restrict__ ridx) {
  int n = blockIdx.x;
  int lane = threadIdx.x;
  const unsigned long long* S = sup + (size_t)n * PREN * 64;
  unsigned long long buf[64];
#pragma unroll
  for (int bq = 0; bq < 64; ++bq) buf[bq] = S[(size_t)bq * 64 + lane];
  unsigned long long keep = (lane < 46) ? ~0ull
                          : (lane == 46 ? ((1ull << 56) - 1ull) : 0ull);  // 3000 bits
  for (int w = 0; w < 47; ++w) {
    unsigned long long kw = __shfl(keep, w);
    unsigned long long gtmask = (lane > w) ? ~0ull : 0ull;
#pragma unroll
    for (int bq = 0; bq < 64; ++bq) {
      const int i = w * 64 + bq;
      unsigned long long r = buf[bq];
      if (i + 64 < PREN) buf[bq] = S[(size_t)(i + 64) * 64 + lane];
      unsigned long long rw = __shfl(r, w);
      unsigned long long amask = ((kw >> bq) & 1ull) ? ~0ull : 0ull;
      const unsigned long long fmask = (bq == 63) ? 0ull : ~((2ull << bq) - 1ull);
      kw &= ~(rw & fmask & amask);
      keep &= ~(r & gtmask & amask);
    }
    keep = (lane == w) ? kw : keep;
  }
  int cnt = __popcll(keep);
  int scn = cnt;
  for (int d = 1; d < 64; d <<= 1) {
    int v = __shfl_up(scn, d);
    if (lane >= d) scn += v;
  }
  int excl = scn - cnt;
  int total = __shfl(scn, 63);
  const float* SB = sboxes + (size_t)n * PREN * 4;
  unsigned long long kk = keep;
  int p = excl;
  while (kk) {
    int bpos = __ffsll(kk) - 1;
    kk &= kk - 1ull;
    if (p < POSTN) {
      float4 bb = *(const float4*)(SB + (size_t)(lane * 64 + bpos) * 4);
      *(float4*)(rois + ((size_t)n * POSTN + p) * 4) = bb;
    }
    ++p;
  }
  if (lane == 0) {
    float4 b0 = *(const float4*)SB;
    for (int q = total; q < POSTN; ++q)
      *(float4*)(rois + ((size_t)n * POSTN + q) * 4) = b0;
  }
  for (int q = lane; q < POSTN; q += 64) ridx[n * POSTN + q] = (float)n;
}

extern "C" void kernel_launch(void* const* d_in, const int* in_sizes, int n_in,
                              void* d_out, int out_size, void* d_ws, size_t ws_size,
                              hipStream_t stream) {
  const float* x       = (const float*)d_in[0];
  const float* w_conv  = (const float*)d_in[1];
  const float* b_conv  = (const float*)d_in[2];
  const float* w_score = (const float*)d_in[3];
  const float* b_score = (const float*)d_in[4];
  const float* w_loc   = (const float*)d_in[5];
  const float* b_loc   = (const float*)d_in[6];
  const int*   img_h   = (const int*)d_in[7];
  const int*   img_w   = (const int*)d_in[8];

  float* out        = (float*)d_out;
  float* out_locs   = out;                 // (4,36864,4)  589824
  float* out_scores = out + 589824;        // (4,36864,2)  294912
  float* out_rois   = out + 884736;        // (4,300,4)      4800
  float* out_ridx   = out + 889536;        // (4,300)        1200
  float* out_anchor = out + 890736;        // (1,36864,4)  147456

  // ws: feat2 33.55MB | region A: w4 9.44MB (dead after conv3) aliased by
  // boxes/keys/sboxes/sup (9.28MB) | hist 1MB + cut/cnt | cand 1.18MB
  float* feat2 = (float*)d_ws;                            // 8388608 f32
  float* A     = feat2 + (size_t)8388608;
  float* w4    = A;                                       // 2359296 f32
  float* boxes = A;                                       // 589824 f32
  unsigned* keys = (unsigned*)(boxes + 589824);           // 147456 u32
  float* sboxes  = (float*)(keys + 147456);               // 48000 f32
  unsigned long long* sup = (unsigned long long*)(sboxes + 48000); // 768000 u64
  unsigned* hist = (unsigned*)(A + 2359296);              // 262144 u32
  unsigned* cut  = hist + 262144;                         // 4 u32
  unsigned* cnt  = cut + 4;                               // 4 u32 (+pad)
  unsigned long long* cand = (unsigned long long*)(hist + 262144 + 16); // 147456 u64

  hipMemsetAsync(hist, 0, 262144 * 4 + 64, stream);       // hist + cut + cnt
  reshape_w_kernel<<<9216, 256, 0, stream>>>(w_conv, w4);
  conv3_kernel<<<dim3(16, 32, 4), 256, 0, stream>>>(x, w4, b_conv, feat2);
  conv1_decode_kernel<<<dim3(64, 4), 256, 0, stream>>>(
      feat2, w_loc, b_loc, w_score, b_score, img_h, img_w,
      out_locs, out_scores, boxes, keys, hist, out_anchor);
  scan_kernel<<<4, 256, 0, stream>>>(hist, cut);
  compact_kernel<<<576, 256, 0, stream>>>(keys, cut, cnt, cand);
  rank2_kernel<<<dim3(144, 4), 256, 0, stream>>>(cand, cnt, boxes, sboxes);
  iou_kernel<<<dim3(PREN, 4), 256, 0, stream>>>(sboxes, sup);
  nms_kernel<<<4, 64, 0, stream>>>(sup, sboxes, out_rois, out_ridx);
}

// Round 10
// 1375.605 us; speedup vs baseline: 1.0923x; 1.0923x over previous
//
#include <hip/hip_runtime.h>
#include <cstdint>
#include <cmath>

#define HW 64
#define NPIX 4096          // 64*64
#define CIN 512
#define NANCH 36864        // 4096*9
#define PREN 3000
#define POSTN 300
#define ICL 8

// ------ W reshape: w[oc][ic][3][3] -> w4[g][ic][h][tap][o4] ---------------
// g = oct*4 + wid (64 groups of 8 oc), oc = (g>>2)*32 + (g&3)*8 + h*4 + o4
__global__ __launch_bounds__(256) void reshape_w_kernel(
    const float* __restrict__ w, float* __restrict__ w4) {
  int gid = blockIdx.x * 256 + threadIdx.x;
  if (gid >= 512 * 512 * 9) return;
  int o4  = gid & 3;
  int r   = gid >> 2;          // ((g*512+ic)*2+h)*9 + tap
  int tap = r % 9;
  int r2  = r / 9;             // (g*512+ic)*2 + h
  int h   = r2 & 1;
  int r3  = r2 >> 1;           // g*512 + ic
  int ic  = r3 & 511;
  int g   = r3 >> 9;
  int oc  = (g >> 2) * 32 + (g & 3) * 8 + h * 4 + o4;
  w4[gid] = w[((size_t)oc * 512 + ic) * 9 + tap];
}

// ---------------- 3x3 conv + bias + ReLU -> feat2 (NHWC) -----------------
// grid (16 oct, 16 ytile, 4 n), block 256 = 4 waves, 4 blocks/CU.
// Wave = 8 oc (SGPR ping-pong weight stream). Lane = 1 row x 4 cols.
// Staging = global_load_lds DMA: one wave-instruction per (icl,row), interior
// cols 1..64; halo cols + edge rows pre-zeroed once (never rewritten).
#define WLOAD(DST, UPTR) do {                                                \
    _Pragma("unroll")                                                        \
    for (int q = 0; q < 36; ++q) (DST)[q] = (UPTR)[q];                       \
  } while (0)

#define CONV_HALF(W, OB) do {                                                \
    _Pragma("unroll")                                                        \
    for (int r = 0; r < 3; ++r)                                              \
    _Pragma("unroll")                                                        \
    for (int kx = 0; kx < 3; ++kx) {                                         \
      _Pragma("unroll")                                                      \
      for (int o = 0; o < 4; ++o) {                                          \
        const float wv = (W)[(r * 3 + kx) * 4 + o];                          \
        _Pragma("unroll")                                                    \
        for (int j = 0; j < 4; ++j)                                          \
          acc[(OB) + o][j] = fmaf(wv, xr[r][j + kx], acc[(OB) + o][j]);      \
      }                                                                      \
    }                                                                        \
  } while (0)

#define GLOAD_LDS4(GP, LP)                                                   \
  __builtin_amdgcn_global_load_lds(                                          \
      (const __attribute__((address_space(1))) void*)(GP),                   \
      (__attribute__((address_space(3))) void*)(LP), 4, 0, 0)

// 48 (icl,row) slots over 4 waves: q=0..11, icl = wid*2 + q/6, row = q%6.
// LDS dest (wave-uniform) = icl*408 + row*68 + 1; lane i -> col 1+i (xx=i).
#define STAGE(XC, BUF) do {                                                  \
    _Pragma("unroll")                                                        \
    for (int q = 0; q < 12; ++q) {                                           \
      const int icl_ = wid * 2 + q / 6;                                      \
      const int row_ = q % 6;                                                \
      const int yy_  = y0 - 1 + row_;                                        \
      if (yy_ >= 0 && yy_ < 64) {                                            \
        GLOAD_LDS4((XC) + icl_ * NPIX + yy_ * 64 + lane,                     \
                   &xs[BUF][icl_ * 408 + row_ * 68 + 1]);                    \
      }                                                                      \
    }                                                                        \
  } while (0)

__global__ __launch_bounds__(256, 4) void conv3_kernel(
    const float* __restrict__ x, const float* __restrict__ w4,
    const float* __restrict__ b, float* __restrict__ feat2) {
  const int oct = blockIdx.x;      // 0..15
  const int yt  = blockIdx.y;      // 0..15
  const int n   = blockIdx.z;
  const int t   = threadIdx.x;
  const int wid  = __builtin_amdgcn_readfirstlane(t >> 6);
  const int lane = t & 63;
  const int lrow = lane >> 4;          // 0..3
  const int lcol = (lane & 15) << 2;   // 0..60
  const int y0 = yt << 2;

  __shared__ float xs[2][ICL * 6 * 68];   // 2 x 13056 B

  float acc[8][4];
#pragma unroll
  for (int o = 0; o < 8; ++o)
#pragma unroll
    for (int j = 0; j < 4; ++j) acc[o][j] = 0.f;

  const float* xb = x + (size_t)n * CIN * NPIX;
  const float* __restrict__ wq = w4 + (size_t)(oct * 4 + wid) * (512 * 72);

  // ---- zero both buffers once (halo cols 0,65..67 + edge rows persist) ----
  for (int idx = t; idx < 2 * ICL * 6 * 68; idx += 256)
    ((float*)xs)[idx] = 0.f;
  __syncthreads();                        // zeros visible before any DMA

  STAGE(xb, 0);                           // prologue: chunk 0 -> buf 0

  float wbA[36], wbB[36];
  WLOAD(wbA, wq);                         // unit 0

  for (int cch = 0; cch < 64; ++cch) {
    const int cur = cch & 1;
    __syncthreads();                      // drains this wave's DMA (vmcnt) + sync
    if (cch < 63) {                       // DMA next chunk into other buffer
      const float* xn = xb + (size_t)(cch + 1) * (ICL * NPIX);
      STAGE(xn, cur ^ 1);
    }
#pragma unroll 1
    for (int icl = 0; icl < ICL; ++icl) {
      const int u0 = (cch << 4) + (icl << 1);    // unit in wbA
      const float* xp = &xs[cur][icl * 408 + lrow * 68 + lcol];
      float4 a0 = *(const float4*)(xp);
      float2 b0 = *(const float2*)(xp + 4);
      float4 a1 = *(const float4*)(xp + 68);
      float2 b1 = *(const float2*)(xp + 72);
      float4 a2 = *(const float4*)(xp + 136);
      float2 b2 = *(const float2*)(xp + 140);
      float xr[3][6] = {{a0.x, a0.y, a0.z, a0.w, b0.x, b0.y},
                        {a1.x, a1.y, a1.z, a1.w, b1.x, b1.y},
                        {a2.x, a2.y, a2.z, a2.w, b2.x, b2.y}};
      WLOAD(wbB, wq + (size_t)(u0 + 1) * 36);    // prefetch half B
      CONV_HALF(wbA, 0);                         // oc 0..3 (144 FMA)
      {
        const int un = (u0 + 2 < 1024) ? (u0 + 2) : 1023;
        WLOAD(wbA, wq + (size_t)un * 36);        // prefetch next half A
      }
      CONV_HALF(wbB, 4);                         // oc 4..7 (144 FMA)
    }
  }

  const float* __restrict__ bs = b + oct * 32 + wid * 8;  // uniform
  float bias[8];
#pragma unroll
  for (int o = 0; o < 8; ++o) bias[o] = bs[o];
  float* ob = feat2 + ((size_t)n * NPIX + (y0 + lrow) * 64 + lcol) * 512 + oct * 32 + wid * 8;
#pragma unroll
  for (int j = 0; j < 4; ++j) {
    float4 v0, v1;
    v0.x = fmaxf(acc[0][j] + bias[0], 0.f);
    v0.y = fmaxf(acc[1][j] + bias[1], 0.f);
    v0.z = fmaxf(acc[2][j] + bias[2], 0.f);
    v0.w = fmaxf(acc[3][j] + bias[3], 0.f);
    v1.x = fmaxf(acc[4][j] + bias[4], 0.f);
    v1.y = fmaxf(acc[5][j] + bias[5], 0.f);
    v1.z = fmaxf(acc[6][j] + bias[6], 0.f);
    v1.w = fmaxf(acc[7][j] + bias[7], 0.f);
    *(float4*)(ob + (size_t)j * 512)     = v0;
    *(float4*)(ob + (size_t)j * 512 + 4) = v1;
  }
}

// ---- 1x1 convs + bias -> outputs, FUSED with decode/softmax/keys/hist ----
__global__ __launch_bounds__(256) void conv1_decode_kernel(
    const float* __restrict__ feat2,
    const float* __restrict__ w_loc, const float* __restrict__ b_loc,
    const float* __restrict__ w_score, const float* __restrict__ b_score,
    const int* __restrict__ ih, const int* __restrict__ iw,
    float* __restrict__ out_locs, float* __restrict__ out_scores,
    float* __restrict__ boxes, unsigned* __restrict__ keys,
    unsigned* __restrict__ hist, float* __restrict__ out_anchor) {
#pragma clang fp contract(off)
  const int y = blockIdx.x, n = blockIdx.y;
  const int t = threadIdx.x;
  const int px = t & 63, grp = t >> 6;
  const int lane = t & 63;
  __shared__ float fl[64 * 129];
  __shared__ float wl[54 * 128];           // reused as [px][54] stash after GEMM
  float acc[14];
#pragma unroll
  for (int k = 0; k < 14; ++k) acc[k] = 0.f;
  const float* fb = feat2 + ((size_t)n * NPIX + y * 64) * 512;
  for (int ch = 0; ch < 512; ch += 128) {
    for (int idx = t; idx < 64 * 128; idx += 256) {
      int p = idx >> 7, ic = idx & 127;
      fl[p * 129 + ic] = fb[(size_t)p * 512 + ch + ic];
    }
    for (int idx = t; idx < 54 * 128; idx += 256) {
      int c = idx >> 7, ic = idx & 127;
      wl[c * 128 + ic] = (c < 36) ? w_loc[c * 512 + ch + ic]
                                  : w_score[(c - 36) * 512 + ch + ic];
    }
    __syncthreads();
#pragma unroll 4
    for (int ic = 0; ic < 128; ++ic) {
      float f = fl[px * 129 + ic];
#pragma unroll
      for (int k = 0; k < 14; ++k) {
        int c = grp + 4 * k;
        if (c < 54) acc[k] = fmaf(wl[c * 128 + ic], f, acc[k]);
      }
    }
    __syncthreads();
  }
  size_t pix0 = (size_t)y * 64 + px;
#pragma unroll
  for (int k = 0; k < 14; ++k) {
    int c = grp + 4 * k;
    if (c < 36) {
      float v = acc[k] + b_loc[c];
      out_locs[((size_t)n * NPIX + pix0) * 36 + c] = v;
      wl[px * 54 + c] = v;
    } else if (c < 54) {
      float v = acc[k] + b_score[c - 36];
      out_scores[((size_t)n * NPIX + pix0) * 18 + (c - 36)] = v;
      wl[px * 54 + c] = v;
    }
  }
  __syncthreads();
  // ---- decode: 576 tasks (64 px x 9 anchors) over 256 threads ----
  for (int task = t; task < 576; task += 256) {
    int lpx = task / 9;
    int a   = task - lpx * 9;
    int xq = lpx, yq = y;
    int i = (yq * 64 + xq) * 9 + a;
    int gid = n * NANCH + i;
    int ri = a / 3, si = a - ri * 3;
    double ratio = (ri == 0) ? 0.5 : (ri == 1 ? 1.0 : 2.0);
    double scl   = (si == 0) ? 8.0 : (si == 1 ? 16.0 : 32.0);
    double hh = 16.0 * scl * sqrt(ratio);
    double ww = 16.0 * scl * sqrt(1.0 / ratio);
    float sx = (float)(xq * 16), sy = (float)(yq * 16);
    float ax1 = (float)(8.0 - ww * 0.5) + sx;
    float ay1 = (float)(8.0 - hh * 0.5) + sy;
    float ax2 = (float)(8.0 + ww * 0.5) + sx;
    float ay2 = (float)(8.0 + hh * 0.5) + sy;
    if (n == 0) {
      *(float4*)(out_anchor + (size_t)i * 4) = make_float4(ax1, ay1, ax2, ay2);
    }
    float l0 = wl[lpx * 54 + a * 4 + 0];
    float l1 = wl[lpx * 54 + a * 4 + 1];
    float l2 = wl[lpx * 54 + a * 4 + 2];
    float l3 = wl[lpx * 54 + a * 4 + 3];
    float aw = ax2 - ax1, ah = ay2 - ay1;
    float cx = ax1 + 0.5f * aw, cy = ay1 + 0.5f * ah;
    float ctrx = l0 * aw + cx, ctry = l1 * ah + cy;
    float nw = expf(l2) * aw, nh = expf(l3) * ah;
    float x1 = ctrx - 0.5f * nw, y1 = ctry - 0.5f * nh;
    float x2 = ctrx + 0.5f * nw, y2 = ctry + 0.5f * nh;
    float W = (float)iw[0], H = (float)ih[0];
    x1 = fminf(fmaxf(x1, 0.f), W);
    y1 = fminf(fmaxf(y1, 0.f), H);
    x2 = fminf(fmaxf(x2, 0.f), W);
    y2 = fminf(fmaxf(y2, 0.f), H);
    bool valid = ((x2 - x1) >= 16.f) && ((y2 - y1) >= 16.f);
    float s0 = wl[lpx * 54 + 36 + a * 2];
    float s1 = wl[lpx * 54 + 36 + a * 2 + 1];
    float mx = fmaxf(s0, s1);
    float e0 = expf(s0 - mx), e1 = expf(s1 - mx);
    float fg = e1 / (e0 + e1);
    float sc = valid ? fg : -1e9f;
    unsigned bb = __float_as_uint(sc);
    unsigned v = (bb & 0x80000000u) ? ~bb : (bb | 0x80000000u);  // ascending
    keys[gid] = v;
    *(float4*)(boxes + (size_t)gid * 4) = make_float4(x1, y1, x2, y2);
    unsigned bin = v >> 16;
    unsigned long long mv = __ballot(!valid);   // invalid => one shared bin
    if (!valid) {
      int leader = __ffsll(mv) - 1;
      if (lane == leader)
        atomicAdd(&hist[(size_t)n * 65536 + bin], (unsigned)__popcll(mv));
    } else {
      atomicAdd(&hist[(size_t)n * 65536 + bin], 1u);
    }
  }
}

// ------- find threshold bin P: count(v>>16 >= P) >= PREN, minimal set -----
__global__ __launch_bounds__(256) void scan_kernel(
    const unsigned* __restrict__ hist, unsigned* __restrict__ cut) {
  int n = blockIdx.x;
  int t = threadIdx.x;
  const unsigned* h = hist + (size_t)n * 65536;
  __shared__ unsigned csum[256];
  __shared__ unsigned fine[256];
  __shared__ unsigned csel, cumsh;
  unsigned s = 0;
  for (int bq = 0; bq < 256; ++bq) s += h[t * 256 + bq];
  csum[t] = s;
  __syncthreads();
  if (t == 0) {
    unsigned cum = 0;
    int c = 255;
    for (; c > 0; --c) {
      if (cum + csum[c] >= PREN) break;
      cum += csum[c];
    }
    csel = (unsigned)c;
    cumsh = cum;
  }
  __syncthreads();
  int c = (int)csel;
  fine[t] = h[c * 256 + t];               // parallel, coalesced
  __syncthreads();
  if (t == 0) {
    unsigned cum = cumsh;
    unsigned P = (unsigned)(c * 256);
    for (int bq = 255; bq >= 0; --bq) {
      cum += fine[bq];
      if (cum >= PREN) { P = (unsigned)(c * 256 + bq); break; }
    }
    cut[n] = P;
  }
}

// ---- compact candidates (v>>16 >= P) with wave-aggregated atomics --------
__global__ __launch_bounds__(256) void compact_kernel(
    const unsigned* __restrict__ keys, const unsigned* __restrict__ cut,
    unsigned* __restrict__ cnt, unsigned long long* __restrict__ cand) {
  int gid = blockIdx.x * 256 + threadIdx.x;
  int lane = threadIdx.x & 63;
  int n = gid / NANCH;
  int i = gid - n * NANCH;
  unsigned v = keys[gid];
  bool take = (v >> 16) >= cut[n];
  unsigned long long m = __ballot(take);
  if (take) {
    int leader = __ffsll(m) - 1;
    int tot = __popcll(m);
    int pre = __popcll(m & ((lane == 0) ? 0ull : (~0ull >> (64 - lane))));
    unsigned base = 0;
    if (lane == leader) base = atomicAdd(&cnt[n], (unsigned)tot);
    base = __shfl(base, leader);
    cand[(size_t)n * NANCH + base + pre] =
        ((unsigned long long)v << 32) | (unsigned)(~i);
  }
}

// ---- exact rank among candidates (== global rank) -> score-sorted boxes --
__global__ __launch_bounds__(256) void rank2_kernel(
    const unsigned long long* __restrict__ cand, const unsigned* __restrict__ cnt,
    const float* __restrict__ boxes, float* __restrict__ sboxes) {
  int n = blockIdx.y;
  int C = (int)cnt[n];
  if (blockIdx.x * 256 >= C) return;
  int t = threadIdx.x;
  int i = blockIdx.x * 256 + t;
  const unsigned long long* cb = cand + (size_t)n * NANCH;
  unsigned long long Ki = (i < C) ? cb[i] : 0ull;
  __shared__ unsigned long long tile[256];
  int rank = 0;
  for (int t0 = 0; t0 < C; t0 += 256) {
    __syncthreads();
    int j = t0 + t;
    tile[t] = (j < C) ? cb[j] : 0ull;
    __syncthreads();
#pragma unroll 16
    for (int jj = 0; jj < 256; ++jj)
      rank += (tile[jj] > Ki) ? 1 : 0;
  }
  if (i < C && rank < PREN) {
    unsigned orig = ~(unsigned)(Ki & 0xffffffffull);
    float4 bb = *(const float4*)(boxes + ((size_t)n * NANCH + orig) * 4);
    *(float4*)(sboxes + ((size_t)n * PREN + rank) * 4) = bb;
  }
}

// ------------------ suppression bit-matrix (IoU > 0.7) --------------------
__global__ __launch_bounds__(256) void iou_kernel(
    const float* __restrict__ sboxes, unsigned long long* __restrict__ sup) {
#pragma clang fp contract(off)
  int n = blockIdx.y, i = blockIdx.x;
  const float* B = sboxes + (size_t)n * PREN * 4;
  float4 bi = *(const float4*)(B + (size_t)i * 4);
  float area_i = (bi.z - bi.x) * (bi.w - bi.y);
  int lane = threadIdx.x & 63, wv = threadIdx.x >> 6;
  unsigned long long* row = sup + ((size_t)n * PREN + i) * 64;
  for (int w0 = wv; w0 < 64; w0 += 4) {
    int j = w0 * 64 + lane;
    bool p = false;
    if (j < PREN) {
      float4 bj = *(const float4*)(B + (size_t)j * 4);
      float area_j = (bj.z - bj.x) * (bj.w - bj.y);
      float x1 = fmaxf(bi.x, bj.x), y1 = fmaxf(bi.y, bj.y);
      float x2 = fminf(bi.z, bj.z), y2 = fminf(bi.w, bj.w);
      float inter = fmaxf(x2 - x1, 0.f) * fmaxf(y2 - y1, 0.f);
      float iou = inter / (area_i + area_j - inter + 1e-9f);
      p = iou > 0.7f;
    }
    unsigned long long m = __ballot(p);
    if (lane == 0) row[w0] = m;
  }
}

// -------- word-wise greedy sweep (1 wave/image) + emit 300 rois -----------
__global__ __launch_bounds__(64) void nms_kernel(
    const unsigned long long* __restrict__ sup, const float* __restrict__ sboxes,
    float* __restrict__ rois, float* __restrict__ ridx) {
  int n = blockIdx.x;
  int lane = threadIdx.x;
  const unsigned long long* S = sup + (size_t)n * PREN * 64;
  unsigned long long buf[64];
#pragma unroll
  for (int bq = 0; bq < 64; ++bq) buf[bq] = S[(size_t)bq * 64 + lane];
  unsigned long long keep = (lane < 46) ? ~0ull
                          : (lane == 46 ? ((1ull << 56) - 1ull) : 0ull);  // 3000 bits
  for (int w = 0; w < 47; ++w) {
    unsigned long long kw = __shfl(keep, w);
    unsigned long long gtmask = (lane > w) ? ~0ull : 0ull;
#pragma unroll
    for (int bq = 0; bq < 64; ++bq) {
      const int i = w * 64 + bq;
      unsigned long long r = buf[bq];
      if (i + 64 < PREN) buf[bq] = S[(size_t)(i + 64) * 64 + lane];
      unsigned long long rw = __shfl(r, w);
      unsigned long long amask = ((kw >> bq) & 1ull) ? ~0ull : 0ull;
      const unsigned long long fmask = (bq == 63) ? 0ull : ~((2ull << bq) - 1ull);
      kw &= ~(rw & fmask & amask);
      keep &= ~(r & gtmask & amask);
    }
    keep = (lane == w) ? kw : keep;
  }
  int cnt = __popcll(keep);
  int scn = cnt;
  for (int d = 1; d < 64; d <<= 1) {
    int v = __shfl_up(scn, d);
    if (lane >= d) scn += v;
  }
  int excl = scn - cnt;
  int total = __shfl(scn, 63);
  const float* SB = sboxes + (size_t)n * PREN * 4;
  unsigned long long kk = keep;
  int p = excl;
  while (kk) {
    int bpos = __ffsll(kk) - 1;
    kk &= kk - 1ull;
    if (p < POSTN) {
      float4 bb = *(const float4*)(SB + (size_t)(lane * 64 + bpos) * 4);
      *(float4*)(rois + ((size_t)n * POSTN + p) * 4) = bb;
    }
    ++p;
  }
  if (lane == 0) {
    float4 b0 = *(const float4*)SB;
    for (int q = total; q < POSTN; ++q)
      *(float4*)(rois + ((size_t)n * POSTN + q) * 4) = b0;
  }
  for (int q = lane; q < POSTN; q += 64) ridx[n * POSTN + q] = (float)n;
}

extern "C" void kernel_launch(void* const* d_in, const int* in_sizes, int n_in,
                              void* d_out, int out_size, void* d_ws, size_t ws_size,
                              hipStream_t stream) {
  const float* x       = (const float*)d_in[0];
  const float* w_conv  = (const float*)d_in[1];
  const float* b_conv  = (const float*)d_in[2];
  const float* w_score = (const float*)d_in[3];
  const float* b_score = (const float*)d_in[4];
  const float* w_loc   = (const float*)d_in[5];
  const float* b_loc   = (const float*)d_in[6];
  const int*   img_h   = (const int*)d_in[7];
  const int*   img_w   = (const int*)d_in[8];

  float* out        = (float*)d_out;
  float* out_locs   = out;                 // (4,36864,4)  589824
  float* out_scores = out + 589824;        // (4,36864,2)  294912
  float* out_rois   = out + 884736;        // (4,300,4)      4800
  float* out_ridx   = out + 889536;        // (4,300)        1200
  float* out_anchor = out + 890736;        // (1,36864,4)  147456

  // ws: feat2 33.55MB | region A: w4 9.44MB (dead after conv3) aliased by
  // boxes/keys/sboxes/sup (9.28MB) | hist 1MB + cut/cnt | cand 1.18MB
  float* feat2 = (float*)d_ws;                            // 8388608 f32
  float* A     = feat2 + (size_t)8388608;
  float* w4    = A;                                       // 2359296 f32
  float* boxes = A;                                       // 589824 f32
  unsigned* keys = (unsigned*)(boxes + 589824);           // 147456 u32
  float* sboxes  = (float*)(keys + 147456);               // 48000 f32
  unsigned long long* sup = (unsigned long long*)(sboxes + 48000); // 768000 u64
  unsigned* hist = (unsigned*)(A + 2359296);              // 262144 u32
  unsigned* cut  = hist + 262144;                         // 4 u32
  unsigned* cnt  = cut + 4;                               // 4 u32 (+pad)
  unsigned long long* cand = (unsigned long long*)(hist + 262144 + 16); // 147456 u64

  hipMemsetAsync(hist, 0, 262144 * 4 + 64, stream);       // hist + cut + cnt
  reshape_w_kernel<<<9216, 256, 0, stream>>>(w_conv, w4);
  conv3_kernel<<<dim3(16, 16, 4), 256, 0, stream>>>(x, w4, b_conv, feat2);
  conv1_decode_kernel<<<dim3(64, 4), 256, 0, stream>>>(
      feat2, w_loc, b_loc, w_score, b_score, img_h, img_w,
      out_locs, out_scores, boxes, keys, hist, out_anchor);
  scan_kernel<<<4, 256, 0, stream>>>(hist, cut);
  compact_kernel<<<576, 256, 0, stream>>>(keys, cut, cnt, cand);
  rank2_kernel<<<dim3(144, 4), 256, 0, stream>>>(cand, cnt, boxes, sboxes);
  iou_kernel<<<dim3(PREN, 4), 256, 0, stream>>>(sboxes, sup);
  nms_kernel<<<4, 64, 0, stream>>>(sup, sboxes, out_rois, out_ridx);
}

// Round 11
// 1302.738 us; speedup vs baseline: 1.1534x; 1.0559x over previous
//
#include <hip/hip_runtime.h>
#include <cstdint>
#include <cmath>

#define HW 64
#define NPIX 4096          // 64*64
#define CIN 512
#define NANCH 36864        // 4096*9
#define PREN 3000
#define POSTN 300
#define ICL 8
#define NSLOT 13           // ceil(8*6*66 / 256), last slot: 96 threads

// ------ W reshape: w[oc][ic][3][3] -> w4[g][ic][h][tap][o4] ---------------
// g = oct*4 + wid (64 groups of 8 oc), oc = (g>>2)*32 + (g&3)*8 + h*4 + o4
__global__ __launch_bounds__(256) void reshape_w_kernel(
    const float* __restrict__ w, float* __restrict__ w4) {
  int gid = blockIdx.x * 256 + threadIdx.x;
  if (gid >= 512 * 512 * 9) return;
  int o4  = gid & 3;
  int r   = gid >> 2;          // ((g*512+ic)*2+h)*9 + tap
  int tap = r % 9;
  int r2  = r / 9;             // (g*512+ic)*2 + h
  int h   = r2 & 1;
  int r3  = r2 >> 1;           // g*512 + ic
  int ic  = r3 & 511;
  int g   = r3 >> 9;
  int oc  = (g >> 2) * 32 + (g & 3) * 8 + h * 4 + o4;
  w4[gid] = w[((size_t)oc * 512 + ic) * 9 + tap];
}

// ---------------- 3x3 conv + bias + ReLU -> feat2 (NHWC) -----------------
// Round-8 champion structure (865 us plateau): grid (16,16,4), 4 blocks/CU,
// wave = 8 oc, SGPR 2x36 ping-pong weight stream, LDS x double-buffer.
#define WLOAD(DST, UPTR) do {                                                \
    _Pragma("unroll")                                                        \
    for (int q = 0; q < 36; ++q) (DST)[q] = (UPTR)[q];                       \
  } while (0)

#define CONV_HALF(W, OB) do {                                                \
    _Pragma("unroll")                                                        \
    for (int r = 0; r < 3; ++r)                                              \
    _Pragma("unroll")                                                        \
    for (int kx = 0; kx < 3; ++kx) {                                         \
      _Pragma("unroll")                                                      \
      for (int o = 0; o < 4; ++o) {                                          \
        const float wv = (W)[(r * 3 + kx) * 4 + o];                          \
        _Pragma("unroll")                                                    \
        for (int j = 0; j < 4; ++j)                                          \
          acc[(OB) + o][j] = fmaf(wv, xr[r][j + kx], acc[(OB) + o][j]);      \
      }                                                                      \
    }                                                                        \
  } while (0)

__global__ __launch_bounds__(256, 4) void conv3_kernel(
    const float* __restrict__ x, const float* __restrict__ w4,
    const float* __restrict__ b, float* __restrict__ feat2) {
  const int oct = blockIdx.x;      // 0..15
  const int yt  = blockIdx.y;      // 0..15
  const int n   = blockIdx.z;
  const int t   = threadIdx.x;
  const int wid  = __builtin_amdgcn_readfirstlane(t >> 6);
  const int lane = t & 63;
  const int lrow = lane >> 4;          // 0..3
  const int lcol = (lane & 15) << 2;   // 0..60
  const int y0 = yt << 2;

  __shared__ float xs[2][ICL * 6 * 68];   // 2 x 13056 B

  float acc[8][4];
#pragma unroll
  for (int o = 0; o < 8; ++o)
#pragma unroll
    for (int j = 0; j < 4; ++j) acc[o][j] = 0.f;

  const float* xb = x + (size_t)n * CIN * NPIX;
  const float* __restrict__ wq = w4 + (size_t)(oct * 4 + wid) * (512 * 72);

  // ---- staging slots (divides once): 8*6*66 = 3168 elems ----
  int  goff[NSLOT];
  int  laddr[NSLOT];
  bool val[NSLOT];
#pragma unroll
  for (int k = 0; k < NSLOT; ++k) {
    int s   = t + (k << 8);
    int icl = s / 396;
    int rem = s - icl * 396;
    int row = rem / 66;
    int c   = rem - row * 66;
    int yy = y0 - 1 + row;
    int xx = c - 1;
    bool act = (k < NSLOT - 1) || (t < 96);
    val[k]  = act && ((unsigned)yy < 64u) && ((unsigned)xx < 64u);
    goff[k] = icl * NPIX + yy * 64 + xx;
    laddr[k] = icl * 408 + row * 68 + c;
  }

  { // prologue: chunk 0 -> buf 0
    float v[NSLOT];
#pragma unroll
    for (int k = 0; k < NSLOT; ++k) v[k] = val[k] ? xb[goff[k]] : 0.f;
#pragma unroll
    for (int k = 0; k < NSLOT; ++k)
      if (k < NSLOT - 1 || t < 96) xs[0][laddr[k]] = v[k];
  }

  float wbA[36], wbB[36];
  WLOAD(wbA, wq);                         // unit 0

  for (int cch = 0; cch < 64; ++cch) {
    const int cur = cch & 1;
    float rn[NSLOT];
    if (cch < 63) {                       // next x chunk issued before barrier
      const float* xn = xb + (size_t)(cch + 1) * (ICL * NPIX);
#pragma unroll
      for (int k = 0; k < NSLOT; ++k) rn[k] = val[k] ? xn[goff[k]] : 0.f;
    }
    __syncthreads();                      // buf[cur] ready
#pragma unroll 1
    for (int icl = 0; icl < ICL; ++icl) {
      const int u0 = (cch << 4) + (icl << 1);    // unit in wbA
      const float* xp = &xs[cur][icl * 408 + lrow * 68 + lcol];
      float4 a0 = *(const float4*)(xp);
      float2 b0 = *(const float2*)(xp + 4);
      float4 a1 = *(const float4*)(xp + 68);
      float2 b1 = *(const float2*)(xp + 72);
      float4 a2 = *(const float4*)(xp + 136);
      float2 b2 = *(const float2*)(xp + 140);
      float xr[3][6] = {{a0.x, a0.y, a0.z, a0.w, b0.x, b0.y},
                        {a1.x, a1.y, a1.z, a1.w, b1.x, b1.y},
                        {a2.x, a2.y, a2.z, a2.w, b2.x, b2.y}};
      WLOAD(wbB, wq + (size_t)(u0 + 1) * 36);    // prefetch half B
      CONV_HALF(wbA, 0);                         // oc 0..3 (144 FMA)
      {
        const int un = (u0 + 2 < 1024) ? (u0 + 2) : 1023;
        WLOAD(wbA, wq + (size_t)un * 36);        // prefetch next half A
      }
      CONV_HALF(wbB, 4);                         // oc 4..7 (144 FMA)
    }
    if (cch < 63) {
#pragma unroll
      for (int k = 0; k < NSLOT; ++k)
        if (k < NSLOT - 1 || t < 96) xs[cur ^ 1][laddr[k]] = rn[k];
    }
  }

  const float* __restrict__ bs = b + oct * 32 + wid * 8;  // uniform
  float bias[8];
#pragma unroll
  for (int o = 0; o < 8; ++o) bias[o] = bs[o];
  float* ob = feat2 + ((size_t)n * NPIX + (y0 + lrow) * 64 + lcol) * 512 + oct * 32 + wid * 8;
#pragma unroll
  for (int j = 0; j < 4; ++j) {
    float4 v0, v1;
    v0.x = fmaxf(acc[0][j] + bias[0], 0.f);
    v0.y = fmaxf(acc[1][j] + bias[1], 0.f);
    v0.z = fmaxf(acc[2][j] + bias[2], 0.f);
    v0.w = fmaxf(acc[3][j] + bias[3], 0.f);
    v1.x = fmaxf(acc[4][j] + bias[4], 0.f);
    v1.y = fmaxf(acc[5][j] + bias[5], 0.f);
    v1.z = fmaxf(acc[6][j] + bias[6], 0.f);
    v1.w = fmaxf(acc[7][j] + bias[7], 0.f);
    *(float4*)(ob + (size_t)j * 512)     = v0;
    *(float4*)(ob + (size_t)j * 512 + 4) = v1;
  }
}

// ---- 1x1 convs + bias + decode/softmax/keys/hist, register-tiled GEMM ----
// Lane = 4 px x 4 ch: per ic, 2x ds_read_b128 + 16 FMA (was 15 ds_reads/14).
// fl2[ic][px] (stride 68), wl2[ic][c] (c padded to 64). Stash reuses fl2.
__global__ __launch_bounds__(256) void conv1_decode_kernel(
    const float* __restrict__ feat2,
    const float* __restrict__ w_loc, const float* __restrict__ b_loc,
    const float* __restrict__ w_score, const float* __restrict__ b_score,
    const int* __restrict__ ih, const int* __restrict__ iw,
    float* __restrict__ out_locs, float* __restrict__ out_scores,
    float* __restrict__ boxes, unsigned* __restrict__ keys,
    unsigned* __restrict__ hist, float* __restrict__ out_anchor) {
#pragma clang fp contract(off)
  const int y = blockIdx.x, n = blockIdx.y;
  const int t = threadIdx.x;
  const int lane = t & 63;
  const int wid = t >> 6;
  const int pg = lane >> 2;            // 0..15 -> px = pg*4..+3
  const int cg = wid * 4 + (lane & 3); // 0..15 -> c  = cg*4..+3 (54..63 pad)
  __shared__ float fl2[128 * 68];      // [ic][px pad 68]  34.8 KB
  __shared__ float wl2[128 * 64];      // [ic][c pad 64]   32.8 KB
  float acc[4][4];                     // [px][ch]
#pragma unroll
  for (int i = 0; i < 4; ++i)
#pragma unroll
    for (int j = 0; j < 4; ++j) acc[i][j] = 0.f;

  const float* fb = feat2 + ((size_t)n * NPIX + y * 64) * 512;
  for (int ch = 0; ch < 512; ch += 128) {
    for (int idx = t; idx < 64 * 128; idx += 256) {       // features
      int p = idx >> 7, ic = idx & 127;                   // lanes -> consec ic
      fl2[ic * 68 + p] = fb[(size_t)p * 512 + ch + ic];
    }
    for (int idx = t; idx < 64 * 128; idx += 256) {       // weights (L2-hot)
      int c = idx & 63, ic = idx >> 6;                    // lanes -> consec c
      float v = 0.f;
      if (c < 36) v = w_loc[c * 512 + ch + ic];
      else if (c < 54) v = w_score[(c - 36) * 512 + ch + ic];
      wl2[ic * 64 + c] = v;
    }
    __syncthreads();
#pragma unroll 4
    for (int ic = 0; ic < 128; ++ic) {
      float4 f = *(const float4*)&fl2[ic * 68 + pg * 4];
      float4 w = *(const float4*)&wl2[ic * 64 + cg * 4];
      float fv[4] = {f.x, f.y, f.z, f.w};
      float wv[4] = {w.x, w.y, w.z, w.w};
#pragma unroll
      for (int i = 0; i < 4; ++i)
#pragma unroll
        for (int j = 0; j < 4; ++j)
          acc[i][j] = fmaf(wv[j], fv[i], acc[i][j]);
    }
    __syncthreads();
  }
  // epilogue: bias + global writes + stash (fl2 reused as [px][56])
#pragma unroll
  for (int j = 0; j < 4; ++j) {
    int c = cg * 4 + j;
    float bias = (c < 36) ? b_loc[c] : (c < 54 ? b_score[c - 36] : 0.f);
#pragma unroll
    for (int i = 0; i < 4; ++i) {
      int px = pg * 4 + i;
      float v = acc[i][j] + bias;
      size_t pix0 = (size_t)y * 64 + px;
      if (c < 36) {
        out_locs[((size_t)n * NPIX + pix0) * 36 + c] = v;
        fl2[px * 56 + c] = v;
      } else if (c < 54) {
        out_scores[((size_t)n * NPIX + pix0) * 18 + (c - 36)] = v;
        fl2[px * 56 + c] = v;
      }
    }
  }
  __syncthreads();
  // ---- decode: 576 tasks (64 px x 9 anchors) over 256 threads ----
  for (int task = t; task < 576; task += 256) {
    int lpx = task / 9;
    int a   = task - lpx * 9;
    int xq = lpx, yq = y;
    int i = (yq * 64 + xq) * 9 + a;
    int gid = n * NANCH + i;
    int ri = a / 3, si = a - ri * 3;
    double ratio = (ri == 0) ? 0.5 : (ri == 1 ? 1.0 : 2.0);
    double scl   = (si == 0) ? 8.0 : (si == 1 ? 16.0 : 32.0);
    double hh = 16.0 * scl * sqrt(ratio);
    double ww = 16.0 * scl * sqrt(1.0 / ratio);
    float sx = (float)(xq * 16), sy = (float)(yq * 16);
    float ax1 = (float)(8.0 - ww * 0.5) + sx;
    float ay1 = (float)(8.0 - hh * 0.5) + sy;
    float ax2 = (float)(8.0 + ww * 0.5) + sx;
    float ay2 = (float)(8.0 + hh * 0.5) + sy;
    if (n == 0) {
      *(float4*)(out_anchor + (size_t)i * 4) = make_float4(ax1, ay1, ax2, ay2);
    }
    float l0 = fl2[lpx * 56 + a * 4 + 0];
    float l1 = fl2[lpx * 56 + a * 4 + 1];
    float l2 = fl2[lpx * 56 + a * 4 + 2];
    float l3 = fl2[lpx * 56 + a * 4 + 3];
    float aw = ax2 - ax1, ah = ay2 - ay1;
    float cx = ax1 + 0.5f * aw, cy = ay1 + 0.5f * ah;
    float ctrx = l0 * aw + cx, ctry = l1 * ah + cy;
    float nw = expf(l2) * aw, nh = expf(l3) * ah;
    float x1 = ctrx - 0.5f * nw, y1 = ctry - 0.5f * nh;
    float x2 = ctrx + 0.5f * nw, y2 = ctry + 0.5f * nh;
    float W = (float)iw[0], H = (float)ih[0];
    x1 = fminf(fmaxf(x1, 0.f), W);
    y1 = fminf(fmaxf(y1, 0.f), H);
    x2 = fminf(fmaxf(x2, 0.f), W);
    y2 = fminf(fmaxf(y2, 0.f), H);
    bool valid = ((x2 - x1) >= 16.f) && ((y2 - y1) >= 16.f);
    float s0 = fl2[lpx * 56 + 36 + a * 2];
    float s1 = fl2[lpx * 56 + 36 + a * 2 + 1];
    float mx = fmaxf(s0, s1);
    float e0 = expf(s0 - mx), e1 = expf(s1 - mx);
    float fg = e1 / (e0 + e1);
    float sc = valid ? fg : -1e9f;
    unsigned bb = __float_as_uint(sc);
    unsigned v = (bb & 0x80000000u) ? ~bb : (bb | 0x80000000u);  // ascending
    keys[gid] = v;
    *(float4*)(boxes + (size_t)gid * 4) = make_float4(x1, y1, x2, y2);
    unsigned bin = v >> 16;
    unsigned long long mv = __ballot(!valid);   // invalid => one shared bin
    if (!valid) {
      int leader = __ffsll(mv) - 1;
      if (lane == leader)
        atomicAdd(&hist[(size_t)n * 65536 + bin], (unsigned)__popcll(mv));
    } else {
      atomicAdd(&hist[(size_t)n * 65536 + bin], 1u);
    }
  }
}

// ------- find threshold bin P: count(v>>16 >= P) >= PREN, minimal set -----
__global__ __launch_bounds__(256) void scan_kernel(
    const unsigned* __restrict__ hist, unsigned* __restrict__ cut) {
  int n = blockIdx.x;
  int t = threadIdx.x;
  const unsigned* h = hist + (size_t)n * 65536;
  __shared__ unsigned csum[256];
  __shared__ unsigned fine[256];
  __shared__ unsigned csel, cumsh;
  unsigned s = 0;
  for (int bq = 0; bq < 256; ++bq) s += h[t * 256 + bq];
  csum[t] = s;
  __syncthreads();
  if (t == 0) {
    unsigned cum = 0;
    int c = 255;
    for (; c > 0; --c) {
      if (cum + csum[c] >= PREN) break;
      cum += csum[c];
    }
    csel = (unsigned)c;
    cumsh = cum;
  }
  __syncthreads();
  int c = (int)csel;
  fine[t] = h[c * 256 + t];               // parallel, coalesced
  __syncthreads();
  if (t == 0) {
    unsigned cum = cumsh;
    unsigned P = (unsigned)(c * 256);
    for (int bq = 255; bq >= 0; --bq) {
      cum += fine[bq];
      if (cum >= PREN) { P = (unsigned)(c * 256 + bq); break; }
    }
    cut[n] = P;
  }
}

// ---- compact candidates (v>>16 >= P) with wave-aggregated atomics --------
__global__ __launch_bounds__(256) void compact_kernel(
    const unsigned* __restrict__ keys, const unsigned* __restrict__ cut,
    unsigned* __restrict__ cnt, unsigned long long* __restrict__ cand) {
  int gid = blockIdx.x * 256 + threadIdx.x;
  int lane = threadIdx.x & 63;
  int n = gid / NANCH;
  int i = gid - n * NANCH;
  unsigned v = keys[gid];
  bool take = (v >> 16) >= cut[n];
  unsigned long long m = __ballot(take);
  if (take) {
    int leader = __ffsll(m) - 1;
    int tot = __popcll(m);
    int pre = __popcll(m & ((lane == 0) ? 0ull : (~0ull >> (64 - lane))));
    unsigned base = 0;
    if (lane == leader) base = atomicAdd(&cnt[n], (unsigned)tot);
    base = __shfl(base, leader);
    cand[(size_t)n * NANCH + base + pre] =
        ((unsigned long long)v << 32) | (unsigned)(~i);
  }
}

// ---- exact rank among candidates (== global rank) -> score-sorted boxes --
__global__ __launch_bounds__(256) void rank2_kernel(
    const unsigned long long* __restrict__ cand, const unsigned* __restrict__ cnt,
    const float* __restrict__ boxes, float* __restrict__ sboxes) {
  int n = blockIdx.y;
  int C = (int)cnt[n];
  if (blockIdx.x * 256 >= C) return;
  int t = threadIdx.x;
  int i = blockIdx.x * 256 + t;
  const unsigned long long* cb = cand + (size_t)n * NANCH;
  unsigned long long Ki = (i < C) ? cb[i] : 0ull;
  __shared__ unsigned long long tile[256];
  int rank = 0;
  for (int t0 = 0; t0 < C; t0 += 256) {
    __syncthreads();
    int j = t0 + t;
    tile[t] = (j < C) ? cb[j] : 0ull;
    __syncthreads();
#pragma unroll 16
    for (int jj = 0; jj < 256; ++jj)
      rank += (tile[jj] > Ki) ? 1 : 0;
  }
  if (i < C && rank < PREN) {
    unsigned orig = ~(unsigned)(Ki & 0xffffffffull);
    float4 bb = *(const float4*)(boxes + ((size_t)n * NANCH + orig) * 4);
    *(float4*)(sboxes + ((size_t)n * PREN + rank) * 4) = bb;
  }
}

// ------------------ suppression bit-matrix (IoU > 0.7) --------------------
__global__ __launch_bounds__(256) void iou_kernel(
    const float* __restrict__ sboxes, unsigned long long* __restrict__ sup) {
#pragma clang fp contract(off)
  int n = blockIdx.y, i = blockIdx.x;
  const float* B = sboxes + (size_t)n * PREN * 4;
  float4 bi = *(const float4*)(B + (size_t)i * 4);
  float area_i = (bi.z - bi.x) * (bi.w - bi.y);
  int lane = threadIdx.x & 63, wv = threadIdx.x >> 6;
  unsigned long long* row = sup + ((size_t)n * PREN + i) * 64;
  for (int w0 = wv; w0 < 64; w0 += 4) {
    int j = w0 * 64 + lane;
    bool p = false;
    if (j < PREN) {
      float4 bj = *(const float4*)(B + (size_t)j * 4);
      float area_j = (bj.z - bj.x) * (bj.w - bj.y);
      float x1 = fmaxf(bi.x, bj.x), y1 = fmaxf(bi.y, bj.y);
      float x2 = fminf(bi.z, bj.z), y2 = fminf(bi.w, bj.w);
      float inter = fmaxf(x2 - x1, 0.f) * fmaxf(y2 - y1, 0.f);
      float iou = inter / (area_i + area_j - inter + 1e-9f);
      p = iou > 0.7f;
    }
    unsigned long long m = __ballot(p);
    if (lane == 0) row[w0] = m;
  }
}

// -------- word-wise greedy sweep (1 wave/image) + emit 300 rois -----------
__global__ __launch_bounds__(64) void nms_kernel(
    const unsigned long long* __restrict__ sup, const float* __restrict__ sboxes,
    float* __restrict__ rois, float* __restrict__ ridx) {
  int n = blockIdx.x;
  int lane = threadIdx.x;
  const unsigned long long* S = sup + (size_t)n * PREN * 64;
  unsigned long long buf[64];
#pragma unroll
  for (int bq = 0; bq < 64; ++bq) buf[bq] = S[(size_t)bq * 64 + lane];
  unsigned long long keep = (lane < 46) ? ~0ull
                          : (lane == 46 ? ((1ull << 56) - 1ull) : 0ull);  // 3000 bits
  for (int w = 0; w < 47; ++w) {
    unsigned long long kw = __shfl(keep, w);
    unsigned long long gtmask = (lane > w) ? ~0ull : 0ull;
#pragma unroll
    for (int bq = 0; bq < 64; ++bq) {
      const int i = w * 64 + bq;
      unsigned long long r = buf[bq];
      if (i + 64 < PREN) buf[bq] = S[(size_t)(i + 64) * 64 + lane];
      unsigned long long rw = __shfl(r, w);
      unsigned long long amask = ((kw >> bq) & 1ull) ? ~0ull : 0ull;
      const unsigned long long fmask = (bq == 63) ? 0ull : ~((2ull << bq) - 1ull);
      kw &= ~(rw & fmask & amask);
      keep &= ~(r & gtmask & amask);
    }
    keep = (lane == w) ? kw : keep;
  }
  int cnt = __popcll(keep);
  int scn = cnt;
  for (int d = 1; d < 64; d <<= 1) {
    int v = __shfl_up(scn, d);
    if (lane >= d) scn += v;
  }
  int excl = scn - cnt;
  int total = __shfl(scn, 63);
  const float* SB = sboxes + (size_t)n * PREN * 4;
  unsigned long long kk = keep;
  int p = excl;
  while (kk) {
    int bpos = __ffsll(kk) - 1;
    kk &= kk - 1ull;
    if (p < POSTN) {
      float4 bb = *(const float4*)(SB + (size_t)(lane * 64 + bpos) * 4);
      *(float4*)(rois + ((size_t)n * POSTN + p) * 4) = bb;
    }
    ++p;
  }
  if (lane == 0) {
    float4 b0 = *(const float4*)SB;
    for (int q = total; q < POSTN; ++q)
      *(float4*)(rois + ((size_t)n * POSTN + q) * 4) = b0;
  }
  for (int q = lane; q < POSTN; q += 64) ridx[n * POSTN + q] = (float)n;
}

extern "C" void kernel_launch(void* const* d_in, const int* in_sizes, int n_in,
                              void* d_out, int out_size, void* d_ws, size_t ws_size,
                              hipStream_t stream) {
  const float* x       = (const float*)d_in[0];
  const float* w_conv  = (const float*)d_in[1];
  const float* b_conv  = (const float*)d_in[2];
  const float* w_score = (const float*)d_in[3];
  const float* b_score = (const float*)d_in[4];
  const float* w_loc   = (const float*)d_in[5];
  const float* b_loc   = (const float*)d_in[6];
  const int*   img_h   = (const int*)d_in[7];
  const int*   img_w   = (const int*)d_in[8];

  float* out        = (float*)d_out;
  float* out_locs   = out;                 // (4,36864,4)  589824
  float* out_scores = out + 589824;        // (4,36864,2)  294912
  float* out_rois   = out + 884736;        // (4,300,4)      4800
  float* out_ridx   = out + 889536;        // (4,300)        1200
  float* out_anchor = out + 890736;        // (1,36864,4)  147456

  // ws: feat2 33.55MB | region A: w4 9.44MB (dead after conv3) aliased by
  // boxes/keys/sboxes/sup (9.28MB) | hist 1MB + cut/cnt | cand 1.18MB
  float* feat2 = (float*)d_ws;                            // 8388608 f32
  float* A     = feat2 + (size_t)8388608;
  float* w4    = A;                                       // 2359296 f32
  float* boxes = A;                                       // 589824 f32
  unsigned* keys = (unsigned*)(boxes + 589824);           // 147456 u32
  float* sboxes  = (float*)(keys + 147456);               // 48000 f32
  unsigned long long* sup = (unsigned long long*)(sboxes + 48000); // 768000 u64
  unsigned* hist = (unsigned*)(A + 2359296);              // 262144 u32
  unsigned* cut  = hist + 262144;                         // 4 u32
  unsigned* cnt  = cut + 4;                               // 4 u32 (+pad)
  unsigned long long* cand = (unsigned long long*)(hist + 262144 + 16); // 147456 u64

  hipMemsetAsync(hist, 0, 262144 * 4 + 64, stream);       // hist + cut + cnt
  reshape_w_kernel<<<9216, 256, 0, stream>>>(w_conv, w4);
  conv3_kernel<<<dim3(16, 16, 4), 256, 0, stream>>>(x, w4, b_conv, feat2);
  conv1_decode_kernel<<<dim3(64, 4), 256, 0, stream>>>(
      feat2, w_loc, b_loc, w_score, b_score, img_h, img_w,
      out_locs, out_scores, boxes, keys, hist, out_anchor);
  scan_kernel<<<4, 256, 0, stream>>>(hist, cut);
  compact_kernel<<<576, 256, 0, stream>>>(keys, cut, cnt, cand);
  rank2_kernel<<<dim3(144, 4), 256, 0, stream>>>(cand, cnt, boxes, sboxes);
  iou_kernel<<<dim3(PREN, 4), 256, 0, stream>>>(sboxes, sup);
  nms_kernel<<<4, 64, 0, stream>>>(sup, sboxes, out_rois, out_ridx);
}

// Round 12
// 1271.965 us; speedup vs baseline: 1.1813x; 1.0242x over previous
//
#include <hip/hip_runtime.h>
#include <cstdint>
#include <cmath>

#define HW 64
#define NPIX 4096          // 64*64
#define CIN 512
#define NANCH 36864        // 4096*9
#define PREN 3000
#define POSTN 300
#define ICL 8
#define NSLOT 13           // ceil(8*6*66 / 256), last slot: 96 threads

// ------ W reshape: w[oc][ic][3][3] -> w4[g][ic][h][tap][o4] ---------------
// g = oct*4 + wid (64 groups of 8 oc), oc = (g>>2)*32 + (g&3)*8 + h*4 + o4
__global__ __launch_bounds__(256) void reshape_w_kernel(
    const float* __restrict__ w, float* __restrict__ w4) {
  int gid = blockIdx.x * 256 + threadIdx.x;
  if (gid >= 512 * 512 * 9) return;
  int o4  = gid & 3;
  int r   = gid >> 2;          // ((g*512+ic)*2+h)*9 + tap
  int tap = r % 9;
  int r2  = r / 9;             // (g*512+ic)*2 + h
  int h   = r2 & 1;
  int r3  = r2 >> 1;           // g*512 + ic
  int ic  = r3 & 511;
  int g   = r3 >> 9;
  int oc  = (g >> 2) * 32 + (g & 3) * 8 + h * 4 + o4;
  w4[gid] = w[((size_t)oc * 512 + ic) * 9 + tap];
}

// ---------------- 3x3 conv + bias + ReLU -> feat2 (NHWC) -----------------
// Round-8 champion structure (865-885 us plateau): grid (16,16,4), 4 blk/CU,
// wave = 8 oc, SGPR 2x36 ping-pong weight stream, LDS x double-buffer.
#define WLOAD(DST, UPTR) do {                                                \
    _Pragma("unroll")                                                        \
    for (int q = 0; q < 36; ++q) (DST)[q] = (UPTR)[q];                       \
  } while (0)

#define CONV_HALF(W, OB) do {                                                \
    _Pragma("unroll")                                                        \
    for (int r = 0; r < 3; ++r)                                              \
    _Pragma("unroll")                                                        \
    for (int kx = 0; kx < 3; ++kx) {                                         \
      _Pragma("unroll")                                                      \
      for (int o = 0; o < 4; ++o) {                                          \
        const float wv = (W)[(r * 3 + kx) * 4 + o];                          \
        _Pragma("unroll")                                                    \
        for (int j = 0; j < 4; ++j)                                          \
          acc[(OB) + o][j] = fmaf(wv, xr[r][j + kx], acc[(OB) + o][j]);      \
      }                                                                      \
    }                                                                        \
  } while (0)

__global__ __launch_bounds__(256, 4) void conv3_kernel(
    const float* __restrict__ x, const float* __restrict__ w4,
    const float* __restrict__ b, float* __restrict__ feat2) {
  const int oct = blockIdx.x;      // 0..15
  const int yt  = blockIdx.y;      // 0..15
  const int n   = blockIdx.z;
  const int t   = threadIdx.x;
  const int wid  = __builtin_amdgcn_readfirstlane(t >> 6);
  const int lane = t & 63;
  const int lrow = lane >> 4;          // 0..3
  const int lcol = (lane & 15) << 2;   // 0..60
  const int y0 = yt << 2;

  __shared__ float xs[2][ICL * 6 * 68];   // 2 x 13056 B

  float acc[8][4];
#pragma unroll
  for (int o = 0; o < 8; ++o)
#pragma unroll
    for (int j = 0; j < 4; ++j) acc[o][j] = 0.f;

  const float* xb = x + (size_t)n * CIN * NPIX;
  const float* __restrict__ wq = w4 + (size_t)(oct * 4 + wid) * (512 * 72);

  // ---- staging slots (divides once): 8*6*66 = 3168 elems ----
  int  goff[NSLOT];
  int  laddr[NSLOT];
  bool val[NSLOT];
#pragma unroll
  for (int k = 0; k < NSLOT; ++k) {
    int s   = t + (k << 8);
    int icl = s / 396;
    int rem = s - icl * 396;
    int row = rem / 66;
    int c   = rem - row * 66;
    int yy = y0 - 1 + row;
    int xx = c - 1;
    bool act = (k < NSLOT - 1) || (t < 96);
    val[k]  = act && ((unsigned)yy < 64u) && ((unsigned)xx < 64u);
    goff[k] = icl * NPIX + yy * 64 + xx;
    laddr[k] = icl * 408 + row * 68 + c;
  }

  { // prologue: chunk 0 -> buf 0
    float v[NSLOT];
#pragma unroll
    for (int k = 0; k < NSLOT; ++k) v[k] = val[k] ? xb[goff[k]] : 0.f;
#pragma unroll
    for (int k = 0; k < NSLOT; ++k)
      if (k < NSLOT - 1 || t < 96) xs[0][laddr[k]] = v[k];
  }

  float wbA[36], wbB[36];
  WLOAD(wbA, wq);                         // unit 0

  for (int cch = 0; cch < 64; ++cch) {
    const int cur = cch & 1;
    float rn[NSLOT];
    if (cch < 63) {                       // next x chunk issued before barrier
      const float* xn = xb + (size_t)(cch + 1) * (ICL * NPIX);
#pragma unroll
      for (int k = 0; k < NSLOT; ++k) rn[k] = val[k] ? xn[goff[k]] : 0.f;
    }
    __syncthreads();                      // buf[cur] ready
#pragma unroll 1
    for (int icl = 0; icl < ICL; ++icl) {
      const int u0 = (cch << 4) + (icl << 1);    // unit in wbA
      const float* xp = &xs[cur][icl * 408 + lrow * 68 + lcol];
      float4 a0 = *(const float4*)(xp);
      float2 b0 = *(const float2*)(xp + 4);
      float4 a1 = *(const float4*)(xp + 68);
      float2 b1 = *(const float2*)(xp + 72);
      float4 a2 = *(const float4*)(xp + 136);
      float2 b2 = *(const float2*)(xp + 140);
      float xr[3][6] = {{a0.x, a0.y, a0.z, a0.w, b0.x, b0.y},
                        {a1.x, a1.y, a1.z, a1.w, b1.x, b1.y},
                        {a2.x, a2.y, a2.z, a2.w, b2.x, b2.y}};
      WLOAD(wbB, wq + (size_t)(u0 + 1) * 36);    // prefetch half B
      CONV_HALF(wbA, 0);                         // oc 0..3 (144 FMA)
      {
        const int un = (u0 + 2 < 1024) ? (u0 + 2) : 1023;
        WLOAD(wbA, wq + (size_t)un * 36);        // prefetch next half A
      }
      CONV_HALF(wbB, 4);                         // oc 4..7 (144 FMA)
    }
    if (cch < 63) {
#pragma unroll
      for (int k = 0; k < NSLOT; ++k)
        if (k < NSLOT - 1 || t < 96) xs[cur ^ 1][laddr[k]] = rn[k];
    }
  }

  const float* __restrict__ bs = b + oct * 32 + wid * 8;  // uniform
  float bias[8];
#pragma unroll
  for (int o = 0; o < 8; ++o) bias[o] = bs[o];
  float* ob = feat2 + ((size_t)n * NPIX + (y0 + lrow) * 64 + lcol) * 512 + oct * 32 + wid * 8;
#pragma unroll
  for (int j = 0; j < 4; ++j) {
    float4 v0, v1;
    v0.x = fmaxf(acc[0][j] + bias[0], 0.f);
    v0.y = fmaxf(acc[1][j] + bias[1], 0.f);
    v0.z = fmaxf(acc[2][j] + bias[2], 0.f);
    v0.w = fmaxf(acc[3][j] + bias[3], 0.f);
    v1.x = fmaxf(acc[4][j] + bias[4], 0.f);
    v1.y = fmaxf(acc[5][j] + bias[5], 0.f);
    v1.z = fmaxf(acc[6][j] + bias[6], 0.f);
    v1.w = fmaxf(acc[7][j] + bias[7], 0.f);
    *(float4*)(ob + (size_t)j * 512)     = v0;
    *(float4*)(ob + (size_t)j * 512 + 4) = v1;
  }
}

// ---- 1x1 convs + bias + decode/softmax/keys/hist, 32 px per block -------
// grid (64 y, 4 n, 2 half) = 512 blocks = 2/CU (8 waves). Lane = 2px x 4ch.
// Per ic: ds_read_b64 (features) + ds_read_b128 (weights) + 8 FMA.
__global__ __launch_bounds__(256) void conv1_decode_kernel(
    const float* __restrict__ feat2,
    const float* __restrict__ w_loc, const float* __restrict__ b_loc,
    const float* __restrict__ w_score, const float* __restrict__ b_score,
    const int* __restrict__ ih, const int* __restrict__ iw,
    float* __restrict__ out_locs, float* __restrict__ out_scores,
    float* __restrict__ boxes, unsigned* __restrict__ keys,
    unsigned* __restrict__ hist, float* __restrict__ out_anchor) {
#pragma clang fp contract(off)
  const int y  = blockIdx.x, n = blockIdx.y, hf = blockIdx.z;
  const int t = threadIdx.x;
  const int lane = t & 63;
  const int pg = t >> 4;               // 0..15 -> px = pg*2, pg*2+1 (local)
  const int cg = t & 15;               // 0..15 -> c = cg*4..+3 (54..63 pad)
  __shared__ float fl2[128 * 34];      // [ic][px pad 34]  17.4 KB
  __shared__ float wl2[128 * 64];      // [ic][c pad 64]   32.8 KB
  float acc[2][4];                     // [px][ch]
#pragma unroll
  for (int i = 0; i < 2; ++i)
#pragma unroll
    for (int j = 0; j < 4; ++j) acc[i][j] = 0.f;

  const float* fb = feat2 + ((size_t)n * NPIX + y * 64 + hf * 32) * 512;
  for (int ch = 0; ch < 512; ch += 128) {
    for (int idx = t; idx < 32 * 128; idx += 256) {       // features
      int p = idx >> 7, ic = idx & 127;                   // lanes -> consec ic
      fl2[ic * 34 + p] = fb[(size_t)p * 512 + ch + ic];
    }
    for (int idx = t; idx < 64 * 128; idx += 256) {       // weights (L2-hot)
      int c = idx & 63, ic = idx >> 6;                    // lanes -> consec c
      float v = 0.f;
      if (c < 36) v = w_loc[c * 512 + ch + ic];
      else if (c < 54) v = w_score[(c - 36) * 512 + ch + ic];
      wl2[ic * 64 + c] = v;
    }
    __syncthreads();
#pragma unroll 4
    for (int ic = 0; ic < 128; ++ic) {
      float2 f = *(const float2*)&fl2[ic * 34 + pg * 2];
      float4 w = *(const float4*)&wl2[ic * 64 + cg * 4];
      float fv[2] = {f.x, f.y};
      float wv[4] = {w.x, w.y, w.z, w.w};
#pragma unroll
      for (int i = 0; i < 2; ++i)
#pragma unroll
        for (int j = 0; j < 4; ++j)
          acc[i][j] = fmaf(wv[j], fv[i], acc[i][j]);
    }
    __syncthreads();
  }
  // epilogue: bias + global writes + stash (fl2 reused as [pxl][56])
#pragma unroll
  for (int j = 0; j < 4; ++j) {
    int c = cg * 4 + j;
    float bias = (c < 36) ? b_loc[c] : (c < 54 ? b_score[c - 36] : 0.f);
#pragma unroll
    for (int i = 0; i < 2; ++i) {
      int pxl = pg * 2 + i;
      float v = acc[i][j] + bias;
      size_t pix0 = (size_t)y * 64 + hf * 32 + pxl;
      if (c < 36) {
        out_locs[((size_t)n * NPIX + pix0) * 36 + c] = v;
        fl2[pxl * 56 + c] = v;
      } else if (c < 54) {
        out_scores[((size_t)n * NPIX + pix0) * 18 + (c - 36)] = v;
        fl2[pxl * 56 + c] = v;
      }
    }
  }
  __syncthreads();
  // ---- decode: 288 tasks (32 px x 9 anchors) over 256 threads ----
  for (int task = t; task < 288; task += 256) {
    int lpx = task / 9;
    int a   = task - lpx * 9;
    int xq = hf * 32 + lpx, yq = y;
    int i = (yq * 64 + xq) * 9 + a;
    int gid = n * NANCH + i;
    int ri = a / 3, si = a - ri * 3;
    double ratio = (ri == 0) ? 0.5 : (ri == 1 ? 1.0 : 2.0);
    double scl   = (si == 0) ? 8.0 : (si == 1 ? 16.0 : 32.0);
    double hh = 16.0 * scl * sqrt(ratio);
    double ww = 16.0 * scl * sqrt(1.0 / ratio);
    float sx = (float)(xq * 16), sy = (float)(yq * 16);
    float ax1 = (float)(8.0 - ww * 0.5) + sx;
    float ay1 = (float)(8.0 - hh * 0.5) + sy;
    float ax2 = (float)(8.0 + ww * 0.5) + sx;
    float ay2 = (float)(8.0 + hh * 0.5) + sy;
    if (n == 0) {
      *(float4*)(out_anchor + (size_t)i * 4) = make_float4(ax1, ay1, ax2, ay2);
    }
    float l0 = fl2[lpx * 56 + a * 4 + 0];
    float l1 = fl2[lpx * 56 + a * 4 + 1];
    float l2 = fl2[lpx * 56 + a * 4 + 2];
    float l3 = fl2[lpx * 56 + a * 4 + 3];
    float aw = ax2 - ax1, ah = ay2 - ay1;
    float cx = ax1 + 0.5f * aw, cy = ay1 + 0.5f * ah;
    float ctrx = l0 * aw + cx, ctry = l1 * ah + cy;
    float nw = expf(l2) * aw, nh = expf(l3) * ah;
    float x1 = ctrx - 0.5f * nw, y1 = ctry - 0.5f * nh;
    float x2 = ctrx + 0.5f * nw, y2 = ctry + 0.5f * nh;
    float W = (float)iw[0], H = (float)ih[0];
    x1 = fminf(fmaxf(x1, 0.f), W);
    y1 = fminf(fmaxf(y1, 0.f), H);
    x2 = fminf(fmaxf(x2, 0.f), W);
    y2 = fminf(fmaxf(y2, 0.f), H);
    bool valid = ((x2 - x1) >= 16.f) && ((y2 - y1) >= 16.f);
    float s0 = fl2[lpx * 56 + 36 + a * 2];
    float s1 = fl2[lpx * 56 + 36 + a * 2 + 1];
    float mx = fmaxf(s0, s1);
    float e0 = expf(s0 - mx), e1 = expf(s1 - mx);
    float fg = e1 / (e0 + e1);
    float sc = valid ? fg : -1e9f;
    unsigned bb = __float_as_uint(sc);
    unsigned v = (bb & 0x80000000u) ? ~bb : (bb | 0x80000000u);  // ascending
    keys[gid] = v;
    *(float4*)(boxes + (size_t)gid * 4) = make_float4(x1, y1, x2, y2);
    unsigned bin = v >> 16;
    unsigned long long mv = __ballot(!valid);   // invalid => one shared bin
    if (!valid) {
      int leader = __ffsll(mv) - 1;
      if (lane == leader)
        atomicAdd(&hist[(size_t)n * 65536 + bin], (unsigned)__popcll(mv));
    } else {
      atomicAdd(&hist[(size_t)n * 65536 + bin], 1u);
    }
  }
}

// ------- find threshold bin P: count(v>>16 >= P) >= PREN, minimal set -----
// 1024 threads: coarse bins of 64 (parallel), then 64-entry fine phase.
__global__ __launch_bounds__(1024) void scan_kernel(
    const unsigned* __restrict__ hist, unsigned* __restrict__ cut) {
  int n = blockIdx.x;
  int t = threadIdx.x;
  const unsigned* h = hist + (size_t)n * 65536;
  __shared__ unsigned csum[1024];
  __shared__ unsigned fine[64];
  __shared__ unsigned csel, cumsh;
  unsigned s = 0;
  for (int bq = 0; bq < 64; ++bq) s += h[t * 64 + bq];
  csum[t] = s;
  __syncthreads();
  if (t == 0) {
    unsigned cum = 0;
    int c = 1023;
    for (; c > 0; --c) {
      if (cum + csum[c] >= PREN) break;
      cum += csum[c];
    }
    csel = (unsigned)c;
    cumsh = cum;
  }
  __syncthreads();
  int c = (int)csel;
  if (t < 64) fine[t] = h[c * 64 + t];    // parallel, coalesced
  __syncthreads();
  if (t == 0) {
    unsigned cum = cumsh;
    unsigned P = (unsigned)(c * 64);
    for (int bq = 63; bq >= 0; --bq) {
      cum += fine[bq];
      if (cum >= PREN) { P = (unsigned)(c * 64 + bq); break; }
    }
    cut[n] = P;
  }
}

// ---- compact candidates (v>>16 >= P) with wave-aggregated atomics --------
__global__ __launch_bounds__(256) void compact_kernel(
    const unsigned* __restrict__ keys, const unsigned* __restrict__ cut,
    unsigned* __restrict__ cnt, unsigned long long* __restrict__ cand) {
  int gid = blockIdx.x * 256 + threadIdx.x;
  int lane = threadIdx.x & 63;
  int n = gid / NANCH;
  int i = gid - n * NANCH;
  unsigned v = keys[gid];
  bool take = (v >> 16) >= cut[n];
  unsigned long long m = __ballot(take);
  if (take) {
    int leader = __ffsll(m) - 1;
    int tot = __popcll(m);
    int pre = __popcll(m & ((lane == 0) ? 0ull : (~0ull >> (64 - lane))));
    unsigned base = 0;
    if (lane == leader) base = atomicAdd(&cnt[n], (unsigned)tot);
    base = __shfl(base, leader);
    cand[(size_t)n * NANCH + base + pre] =
        ((unsigned long long)v << 32) | (unsigned)(~i);
  }
}

// ---- exact rank among candidates (== global rank) -> score-sorted boxes --
__global__ __launch_bounds__(256) void rank2_kernel(
    const unsigned long long* __restrict__ cand, const unsigned* __restrict__ cnt,
    const float* __restrict__ boxes, float* __restrict__ sboxes) {
  int n = blockIdx.y;
  int C = (int)cnt[n];
  if (blockIdx.x * 256 >= C) return;
  int t = threadIdx.x;
  int i = blockIdx.x * 256 + t;
  const unsigned long long* cb = cand + (size_t)n * NANCH;
  unsigned long long Ki = (i < C) ? cb[i] : 0ull;
  __shared__ unsigned long long tile[256];
  int rank = 0;
  for (int t0 = 0; t0 < C; t0 += 256) {
    __syncthreads();
    int j = t0 + t;
    tile[t] = (j < C) ? cb[j] : 0ull;
    __syncthreads();
#pragma unroll 16
    for (int jj = 0; jj < 256; ++jj)
      rank += (tile[jj] > Ki) ? 1 : 0;
  }
  if (i < C && rank < PREN) {
    unsigned orig = ~(unsigned)(Ki & 0xffffffffull);
    float4 bb = *(const float4*)(boxes + ((size_t)n * NANCH + orig) * 4);
    *(float4*)(sboxes + ((size_t)n * PREN + rank) * 4) = bb;
  }
}

// ------------------ suppression bit-matrix (IoU > 0.7) --------------------
__global__ __launch_bounds__(256) void iou_kernel(
    const float* __restrict__ sboxes, unsigned long long* __restrict__ sup) {
#pragma clang fp contract(off)
  int n = blockIdx.y, i = blockIdx.x;
  const float* B = sboxes + (size_t)n * PREN * 4;
  float4 bi = *(const float4*)(B + (size_t)i * 4);
  float area_i = (bi.z - bi.x) * (bi.w - bi.y);
  int lane = threadIdx.x & 63, wv = threadIdx.x >> 6;
  unsigned long long* row = sup + ((size_t)n * PREN + i) * 64;
  for (int w0 = wv; w0 < 64; w0 += 4) {
    int j = w0 * 64 + lane;
    bool p = false;
    if (j < PREN) {
      float4 bj = *(const float4*)(B + (size_t)j * 4);
      float area_j = (bj.z - bj.x) * (bj.w - bj.y);
      float x1 = fmaxf(bi.x, bj.x), y1 = fmaxf(bi.y, bj.y);
      float x2 = fminf(bi.z, bj.z), y2 = fminf(bi.w, bj.w);
      float inter = fmaxf(x2 - x1, 0.f) * fmaxf(y2 - y1, 0.f);
      float iou = inter / (area_i + area_j - inter + 1e-9f);
      p = iou > 0.7f;
    }
    unsigned long long m = __ballot(p);
    if (lane == 0) row[w0] = m;
  }
}

// -------- word-wise greedy sweep (1 wave/image) + emit 300 rois -----------
__global__ __launch_bounds__(64) void nms_kernel(
    const unsigned long long* __restrict__ sup, const float* __restrict__ sboxes,
    float* __restrict__ rois, float* __restrict__ ridx) {
  int n = blockIdx.x;
  int lane = threadIdx.x;
  const unsigned long long* S = sup + (size_t)n * PREN * 64;
  unsigned long long buf[64];
#pragma unroll
  for (int bq = 0; bq < 64; ++bq) buf[bq] = S[(size_t)bq * 64 + lane];
  unsigned long long keep = (lane < 46) ? ~0ull
                          : (lane == 46 ? ((1ull << 56) - 1ull) : 0ull);  // 3000 bits
  for (int w = 0; w < 47; ++w) {
    unsigned long long kw = __shfl(keep, w);
    unsigned long long gtmask = (lane > w) ? ~0ull : 0ull;
#pragma unroll
    for (int bq = 0; bq < 64; ++bq) {
      const int i = w * 64 + bq;
      unsigned long long r = buf[bq];
      if (i + 64 < PREN) buf[bq] = S[(size_t)(i + 64) * 64 + lane];
      unsigned long long rw = __shfl(r, w);
      unsigned long long amask = ((kw >> bq) & 1ull) ? ~0ull : 0ull;
      const unsigned long long fmask = (bq == 63) ? 0ull : ~((2ull << bq) - 1ull);
      kw &= ~(rw & fmask & amask);
      keep &= ~(r & gtmask & amask);
    }
    keep = (lane == w) ? kw : keep;
  }
  int cnt = __popcll(keep);
  int scn = cnt;
  for (int d = 1; d < 64; d <<= 1) {
    int v = __shfl_up(scn, d);
    if (lane >= d) scn += v;
  }
  int excl = scn - cnt;
  int total = __shfl(scn, 63);
  const float* SB = sboxes + (size_t)n * PREN * 4;
  unsigned long long kk = keep;
  int p = excl;
  while (kk) {
    int bpos = __ffsll(kk) - 1;
    kk &= kk - 1ull;
    if (p < POSTN) {
      float4 bb = *(const float4*)(SB + (size_t)(lane * 64 + bpos) * 4);
      *(float4*)(rois + ((size_t)n * POSTN + p) * 4) = bb;
    }
    ++p;
  }
  if (lane == 0) {
    float4 b0 = *(const float4*)SB;
    for (int q = total; q < POSTN; ++q)
      *(float4*)(rois + ((size_t)n * POSTN + q) * 4) = b0;
  }
  for (int q = lane; q < POSTN; q += 64) ridx[n * POSTN + q] = (float)n;
}

extern "C" void kernel_launch(void* const* d_in, const int* in_sizes, int n_in,
                              void* d_out, int out_size, void* d_ws, size_t ws_size,
                              hipStream_t stream) {
  const float* x       = (const float*)d_in[0];
  const float* w_conv  = (const float*)d_in[1];
  const float* b_conv  = (const float*)d_in[2];
  const float* w_score = (const float*)d_in[3];
  const float* b_score = (const float*)d_in[4];
  const float* w_loc   = (const float*)d_in[5];
  const float* b_loc   = (const float*)d_in[6];
  const int*   img_h   = (const int*)d_in[7];
  const int*   img_w   = (const int*)d_in[8];

  float* out        = (float*)d_out;
  float* out_locs   = out;                 // (4,36864,4)  589824
  float* out_scores = out + 589824;        // (4,36864,2)  294912
  float* out_rois   = out + 884736;        // (4,300,4)      4800
  float* out_ridx   = out + 889536;        // (4,300)        1200
  float* out_anchor = out + 890736;        // (1,36864,4)  147456

  // ws: feat2 33.55MB | region A: w4 9.44MB (dead after conv3) aliased by
  // boxes/keys/sboxes/sup (9.28MB) | hist 1MB + cut/cnt | cand 1.18MB
  float* feat2 = (float*)d_ws;                            // 8388608 f32
  float* A     = feat2 + (size_t)8388608;
  float* w4    = A;                                       // 2359296 f32
  float* boxes = A;                                       // 589824 f32
  unsigned* keys = (unsigned*)(boxes + 589824);           // 147456 u32
  float* sboxes  = (float*)(keys + 147456);               // 48000 f32
  unsigned long long* sup = (unsigned long long*)(sboxes + 48000); // 768000 u64
  unsigned* hist = (unsigned*)(A + 2359296);              // 262144 u32
  unsigned* cut  = hist + 262144;                         // 4 u32
  unsigned* cnt  = cut + 4;                               // 4 u32 (+pad)
  unsigned long long* cand = (unsigned long long*)(hist + 262144 + 16); // 147456 u64

  hipMemsetAsync(hist, 0, 262144 * 4 + 64, stream);       // hist + cut + cnt
  reshape_w_kernel<<<9216, 256, 0, stream>>>(w_conv, w4);
  conv3_kernel<<<dim3(16, 16, 4), 256, 0, stream>>>(x, w4, b_conv, feat2);
  conv1_decode_kernel<<<dim3(64, 4, 2), 256, 0, stream>>>(
      feat2, w_loc, b_loc, w_score, b_score, img_h, img_w,
      out_locs, out_scores, boxes, keys, hist, out_anchor);
  scan_kernel<<<4, 1024, 0, stream>>>(hist, cut);
  compact_kernel<<<576, 256, 0, stream>>>(keys, cut, cnt, cand);
  rank2_kernel<<<dim3(144, 4), 256, 0, stream>>>(cand, cnt, boxes, sboxes);
  iou_kernel<<<dim3(PREN, 4), 256, 0, stream>>>(sboxes, sup);
  nms_kernel<<<4, 64, 0, stream>>>(sup, sboxes, out_rois, out_ridx);
}

// Round 13
// 1264.355 us; speedup vs baseline: 1.1884x; 1.0060x over previous
//
#include <hip/hip_runtime.h>
#include <cstdint>
#include <cmath>

#define HW 64
#define NPIX 4096          // 64*64
#define CIN 512
#define NANCH 36864        // 4096*9
#define PREN 3000
#define POSTN 300
#define ICL 8
#define NSLOT 13           // ceil(8*6*66 / 256), last slot: 96 threads

// ------ W reshape + hist/cut/cnt zeroing (folds the memset dispatch) -----
// w[oc][ic][3][3] -> w4[g][ic][h][tap][o4]; g = oct*4+wid, 64 groups of 8 oc
__global__ __launch_bounds__(256) void reshape_w_kernel(
    const float* __restrict__ w, float* __restrict__ w4,
    unsigned* __restrict__ histz) {
  int gid = blockIdx.x * 256 + threadIdx.x;
  if (gid < 262160) histz[gid] = 0;     // hist (transposed) + cut + cnt + pad
  if (gid >= 512 * 512 * 9) return;
  int o4  = gid & 3;
  int r   = gid >> 2;          // ((g*512+ic)*2+h)*9 + tap
  int tap = r % 9;
  int r2  = r / 9;             // (g*512+ic)*2 + h
  int h   = r2 & 1;
  int r3  = r2 >> 1;           // g*512 + ic
  int ic  = r3 & 511;
  int g   = r3 >> 9;
  int oc  = (g >> 2) * 32 + (g & 3) * 8 + h * 4 + o4;
  w4[gid] = w[((size_t)oc * 512 + ic) * 9 + tap];
}

// ---------------- 3x3 conv + bias + ReLU -> feat2 (NHWC) -----------------
// Champion structure (855-893 us plateau, frozen): grid (16,16,4), 4 blk/CU,
// wave = 8 oc, SGPR 2x36 ping-pong weight stream, LDS x double-buffer.
#define WLOAD(DST, UPTR) do {                                                \
    _Pragma("unroll")                                                        \
    for (int q = 0; q < 36; ++q) (DST)[q] = (UPTR)[q];                       \
  } while (0)

#define CONV_HALF(W, OB) do {                                                \
    _Pragma("unroll")                                                        \
    for (int r = 0; r < 3; ++r)                                              \
    _Pragma("unroll")                                                        \
    for (int kx = 0; kx < 3; ++kx) {                                         \
      _Pragma("unroll")                                                      \
      for (int o = 0; o < 4; ++o) {                                          \
        const float wv = (W)[(r * 3 + kx) * 4 + o];                          \
        _Pragma("unroll")                                                    \
        for (int j = 0; j < 4; ++j)                                          \
          acc[(OB) + o][j] = fmaf(wv, xr[r][j + kx], acc[(OB) + o][j]);      \
      }                                                                      \
    }                                                                        \
  } while (0)

__global__ __launch_bounds__(256, 4) void conv3_kernel(
    const float* __restrict__ x, const float* __restrict__ w4,
    const float* __restrict__ b, float* __restrict__ feat2) {
  const int oct = blockIdx.x;      // 0..15
  const int yt  = blockIdx.y;      // 0..15
  const int n   = blockIdx.z;
  const int t   = threadIdx.x;
  const int wid  = __builtin_amdgcn_readfirstlane(t >> 6);
  const int lane = t & 63;
  const int lrow = lane >> 4;          // 0..3
  const int lcol = (lane & 15) << 2;   // 0..60
  const int y0 = yt << 2;

  __shared__ float xs[2][ICL * 6 * 68];   // 2 x 13056 B

  float acc[8][4];
#pragma unroll
  for (int o = 0; o < 8; ++o)
#pragma unroll
    for (int j = 0; j < 4; ++j) acc[o][j] = 0.f;

  const float* xb = x + (size_t)n * CIN * NPIX;
  const float* __restrict__ wq = w4 + (size_t)(oct * 4 + wid) * (512 * 72);

  // ---- staging slots (divides once): 8*6*66 = 3168 elems ----
  int  goff[NSLOT];
  int  laddr[NSLOT];
  bool val[NSLOT];
#pragma unroll
  for (int k = 0; k < NSLOT; ++k) {
    int s   = t + (k << 8);
    int icl = s / 396;
    int rem = s - icl * 396;
    int row = rem / 66;
    int c   = rem - row * 66;
    int yy = y0 - 1 + row;
    int xx = c - 1;
    bool act = (k < NSLOT - 1) || (t < 96);
    val[k]  = act && ((unsigned)yy < 64u) && ((unsigned)xx < 64u);
    goff[k] = icl * NPIX + yy * 64 + xx;
    laddr[k] = icl * 408 + row * 68 + c;
  }

  { // prologue: chunk 0 -> buf 0
    float v[NSLOT];
#pragma unroll
    for (int k = 0; k < NSLOT; ++k) v[k] = val[k] ? xb[goff[k]] : 0.f;
#pragma unroll
    for (int k = 0; k < NSLOT; ++k)
      if (k < NSLOT - 1 || t < 96) xs[0][laddr[k]] = v[k];
  }

  float wbA[36], wbB[36];
  WLOAD(wbA, wq);                         // unit 0

  for (int cch = 0; cch < 64; ++cch) {
    const int cur = cch & 1;
    float rn[NSLOT];
    if (cch < 63) {                       // next x chunk issued before barrier
      const float* xn = xb + (size_t)(cch + 1) * (ICL * NPIX);
#pragma unroll
      for (int k = 0; k < NSLOT; ++k) rn[k] = val[k] ? xn[goff[k]] : 0.f;
    }
    __syncthreads();                      // buf[cur] ready
#pragma unroll 1
    for (int icl = 0; icl < ICL; ++icl) {
      const int u0 = (cch << 4) + (icl << 1);    // unit in wbA
      const float* xp = &xs[cur][icl * 408 + lrow * 68 + lcol];
      float4 a0 = *(const float4*)(xp);
      float2 b0 = *(const float2*)(xp + 4);
      float4 a1 = *(const float4*)(xp + 68);
      float2 b1 = *(const float2*)(xp + 72);
      float4 a2 = *(const float4*)(xp + 136);
      float2 b2 = *(const float2*)(xp + 140);
      float xr[3][6] = {{a0.x, a0.y, a0.z, a0.w, b0.x, b0.y},
                        {a1.x, a1.y, a1.z, a1.w, b1.x, b1.y},
                        {a2.x, a2.y, a2.z, a2.w, b2.x, b2.y}};
      WLOAD(wbB, wq + (size_t)(u0 + 1) * 36);    // prefetch half B
      CONV_HALF(wbA, 0);                         // oc 0..3 (144 FMA)
      {
        const int un = (u0 + 2 < 1024) ? (u0 + 2) : 1023;
        WLOAD(wbA, wq + (size_t)un * 36);        // prefetch next half A
      }
      CONV_HALF(wbB, 4);                         // oc 4..7 (144 FMA)
    }
    if (cch < 63) {
#pragma unroll
      for (int k = 0; k < NSLOT; ++k)
        if (k < NSLOT - 1 || t < 96) xs[cur ^ 1][laddr[k]] = rn[k];
    }
  }

  const float* __restrict__ bs = b + oct * 32 + wid * 8;  // uniform
  float bias[8];
#pragma unroll
  for (int o = 0; o < 8; ++o) bias[o] = bs[o];
  float* ob = feat2 + ((size_t)n * NPIX + (y0 + lrow) * 64 + lcol) * 512 + oct * 32 + wid * 8;
#pragma unroll
  for (int j = 0; j < 4; ++j) {
    float4 v0, v1;
    v0.x = fmaxf(acc[0][j] + bias[0], 0.f);
    v0.y = fmaxf(acc[1][j] + bias[1], 0.f);
    v0.z = fmaxf(acc[2][j] + bias[2], 0.f);
    v0.w = fmaxf(acc[3][j] + bias[3], 0.f);
    v1.x = fmaxf(acc[4][j] + bias[4], 0.f);
    v1.y = fmaxf(acc[5][j] + bias[5], 0.f);
    v1.z = fmaxf(acc[6][j] + bias[6], 0.f);
    v1.w = fmaxf(acc[7][j] + bias[7], 0.f);
    *(float4*)(ob + (size_t)j * 512)     = v0;
    *(float4*)(ob + (size_t)j * 512 + 4) = v1;
  }
}

// ---- 1x1 convs + bias + decode/softmax/keys/hist, 32 px per block -------
// grid (64 y, 4 n, 2 half) = 512 blocks = 2/CU (8 waves). Lane = 2px x 4ch.
// hist is stored TRANSPOSED: index = (bin&255)*256 + (bin>>8), so the
// per-block scan in compact_kernel reads coalesced rows.
__global__ __launch_bounds__(256) void conv1_decode_kernel(
    const float* __restrict__ feat2,
    const float* __restrict__ w_loc, const float* __restrict__ b_loc,
    const float* __restrict__ w_score, const float* __restrict__ b_score,
    const int* __restrict__ ih, const int* __restrict__ iw,
    float* __restrict__ out_locs, float* __restrict__ out_scores,
    float* __restrict__ boxes, unsigned* __restrict__ keys,
    unsigned* __restrict__ hist, float* __restrict__ out_anchor) {
#pragma clang fp contract(off)
  const int y  = blockIdx.x, n = blockIdx.y, hf = blockIdx.z;
  const int t = threadIdx.x;
  const int lane = t & 63;
  const int pg = t >> 4;               // 0..15 -> px = pg*2, pg*2+1 (local)
  const int cg = t & 15;               // 0..15 -> c = cg*4..+3 (54..63 pad)
  __shared__ float fl2[128 * 34];      // [ic][px pad 34]  17.4 KB
  __shared__ float wl2[128 * 64];      // [ic][c pad 64]   32.8 KB
  float acc[2][4];                     // [px][ch]
#pragma unroll
  for (int i = 0; i < 2; ++i)
#pragma unroll
    for (int j = 0; j < 4; ++j) acc[i][j] = 0.f;

  const float* fb = feat2 + ((size_t)n * NPIX + y * 64 + hf * 32) * 512;
  for (int ch = 0; ch < 512; ch += 128) {
    for (int idx = t; idx < 32 * 128; idx += 256) {       // features
      int p = idx >> 7, ic = idx & 127;                   // lanes -> consec ic
      fl2[ic * 34 + p] = fb[(size_t)p * 512 + ch + ic];
    }
    for (int idx = t; idx < 64 * 128; idx += 256) {       // weights (L2-hot)
      int c = idx & 63, ic = idx >> 6;                    // lanes -> consec c
      float v = 0.f;
      if (c < 36) v = w_loc[c * 512 + ch + ic];
      else if (c < 54) v = w_score[(c - 36) * 512 + ch + ic];
      wl2[ic * 64 + c] = v;
    }
    __syncthreads();
#pragma unroll 4
    for (int ic = 0; ic < 128; ++ic) {
      float2 f = *(const float2*)&fl2[ic * 34 + pg * 2];
      float4 w = *(const float4*)&wl2[ic * 64 + cg * 4];
      float fv[2] = {f.x, f.y};
      float wv[4] = {w.x, w.y, w.z, w.w};
#pragma unroll
      for (int i = 0; i < 2; ++i)
#pragma unroll
        for (int j = 0; j < 4; ++j)
          acc[i][j] = fmaf(wv[j], fv[i], acc[i][j]);
    }
    __syncthreads();
  }
  // epilogue: bias + global writes + stash (fl2 reused as [pxl][56])
#pragma unroll
  for (int j = 0; j < 4; ++j) {
    int c = cg * 4 + j;
    float bias = (c < 36) ? b_loc[c] : (c < 54 ? b_score[c - 36] : 0.f);
#pragma unroll
    for (int i = 0; i < 2; ++i) {
      int pxl = pg * 2 + i;
      float v = acc[i][j] + bias;
      size_t pix0 = (size_t)y * 64 + hf * 32 + pxl;
      if (c < 36) {
        out_locs[((size_t)n * NPIX + pix0) * 36 + c] = v;
        fl2[pxl * 56 + c] = v;
      } else if (c < 54) {
        out_scores[((size_t)n * NPIX + pix0) * 18 + (c - 36)] = v;
        fl2[pxl * 56 + c] = v;
      }
    }
  }
  __syncthreads();
  // ---- decode: 288 tasks (32 px x 9 anchors) over 256 threads ----
  for (int task = t; task < 288; task += 256) {
    int lpx = task / 9;
    int a   = task - lpx * 9;
    int xq = hf * 32 + lpx, yq = y;
    int i = (yq * 64 + xq) * 9 + a;
    int gid = n * NANCH + i;
    int ri = a / 3, si = a - ri * 3;
    double ratio = (ri == 0) ? 0.5 : (ri == 1 ? 1.0 : 2.0);
    double scl   = (si == 0) ? 8.0 : (si == 1 ? 16.0 : 32.0);
    double hh = 16.0 * scl * sqrt(ratio);
    double ww = 16.0 * scl * sqrt(1.0 / ratio);
    float sx = (float)(xq * 16), sy = (float)(yq * 16);
    float ax1 = (float)(8.0 - ww * 0.5) + sx;
    float ay1 = (float)(8.0 - hh * 0.5) + sy;
    float ax2 = (float)(8.0 + ww * 0.5) + sx;
    float ay2 = (float)(8.0 + hh * 0.5) + sy;
    if (n == 0) {
      *(float4*)(out_anchor + (size_t)i * 4) = make_float4(ax1, ay1, ax2, ay2);
    }
    float l0 = fl2[lpx * 56 + a * 4 + 0];
    float l1 = fl2[lpx * 56 + a * 4 + 1];
    float l2 = fl2[lpx * 56 + a * 4 + 2];
    float l3 = fl2[lpx * 56 + a * 4 + 3];
    float aw = ax2 - ax1, ah = ay2 - ay1;
    float cx = ax1 + 0.5f * aw, cy = ay1 + 0.5f * ah;
    float ctrx = l0 * aw + cx, ctry = l1 * ah + cy;
    float nw = expf(l2) * aw, nh = expf(l3) * ah;
    float x1 = ctrx - 0.5f * nw, y1 = ctry - 0.5f * nh;
    float x2 = ctrx + 0.5f * nw, y2 = ctry + 0.5f * nh;
    float W = (float)iw[0], H = (float)ih[0];
    x1 = fminf(fmaxf(x1, 0.f), W);
    y1 = fminf(fmaxf(y1, 0.f), H);
    x2 = fminf(fmaxf(x2, 0.f), W);
    y2 = fminf(fmaxf(y2, 0.f), H);
    bool valid = ((x2 - x1) >= 16.f) && ((y2 - y1) >= 16.f);
    float s0 = fl2[lpx * 56 + 36 + a * 2];
    float s1 = fl2[lpx * 56 + 36 + a * 2 + 1];
    float mx = fmaxf(s0, s1);
    float e0 = expf(s0 - mx), e1 = expf(s1 - mx);
    float fg = e1 / (e0 + e1);
    float sc = valid ? fg : -1e9f;
    unsigned bb = __float_as_uint(sc);
    unsigned v = (bb & 0x80000000u) ? ~bb : (bb | 0x80000000u);  // ascending
    keys[gid] = v;
    *(float4*)(boxes + (size_t)gid * 4) = make_float4(x1, y1, x2, y2);
    unsigned bin = v >> 16;
    unsigned tix = ((bin & 255u) << 8) | (bin >> 8);   // transposed index
    unsigned long long mv = __ballot(!valid);   // invalid => one shared bin
    if (!valid) {
      int leader = __ffsll(mv) - 1;
      if (lane == leader)
        atomicAdd(&hist[(size_t)n * 65536 + tix], (unsigned)__popcll(mv));
    } else {
      atomicAdd(&hist[(size_t)n * 65536 + tix], 1u);
    }
  }
}

// ---- compact candidates with INLINE threshold scan (scan launch folded) --
// Each block (256 consecutive gids, single n) recomputes cut deterministically
// from the transposed hist: coarse sums read coalesced rows h[low*256 + t].
__global__ __launch_bounds__(256) void compact_kernel(
    const unsigned* __restrict__ keys, const unsigned* __restrict__ hist,
    unsigned* __restrict__ cnt, unsigned long long* __restrict__ cand) {
  int t = threadIdx.x;
  int gid = blockIdx.x * 256 + t;
  int lane = t & 63;
  int n = (blockIdx.x << 8) / NANCH;          // block-uniform (144 blocks/n)
  int i = gid - n * NANCH;
  const unsigned* h = hist + (size_t)n * 65536;
  __shared__ unsigned csum[256];
  __shared__ unsigned fine[256];
  __shared__ unsigned csel, cumsh, cutsh;
  unsigned s = 0;
  for (int low = 0; low < 256; ++low) s += h[low * 256 + t];   // coalesced
  csum[t] = s;                                // coarse group t = bins t*256+low
  __syncthreads();
  if (t == 0) {
    unsigned cum = 0;
    int c = 255;
    for (; c > 0; --c) {
      if (cum + csum[c] >= PREN) break;
      cum += csum[c];
    }
    csel = (unsigned)c;
    cumsh = cum;
  }
  __syncthreads();
  int c = (int)csel;
  fine[t] = h[t * 256 + c];                   // fine[low] = bin c*256+low
  __syncthreads();
  if (t == 0) {
    unsigned cum = cumsh;
    unsigned P = (unsigned)(c << 8);
    for (int low = 255; low >= 0; --low) {
      cum += fine[low];
      if (cum >= PREN) { P = (unsigned)((c << 8) | low); break; }
    }
    cutsh = P;
  }
  __syncthreads();
  unsigned P = cutsh;
  unsigned v = keys[gid];
  bool take = (v >> 16) >= P;
  unsigned long long m = __ballot(take);
  if (take) {
    int leader = __ffsll(m) - 1;
    int tot = __popcll(m);
    int pre = __popcll(m & ((lane == 0) ? 0ull : (~0ull >> (64 - lane))));
    unsigned base = 0;
    if (lane == leader) base = atomicAdd(&cnt[n], (unsigned)tot);
    base = __shfl(base, leader);
    cand[(size_t)n * NANCH + base + pre] =
        ((unsigned long long)v << 32) | (unsigned)(~i);
  }
}

// ---- exact rank among candidates (== global rank) -> score-sorted boxes --
__global__ __launch_bounds__(256) void rank2_kernel(
    const unsigned long long* __restrict__ cand, const unsigned* __restrict__ cnt,
    const float* __restrict__ boxes, float* __restrict__ sboxes) {
  int n = blockIdx.y;
  int C = (int)cnt[n];
  if (blockIdx.x * 256 >= C) return;
  int t = threadIdx.x;
  int i = blockIdx.x * 256 + t;
  const unsigned long long* cb = cand + (size_t)n * NANCH;
  unsigned long long Ki = (i < C) ? cb[i] : 0ull;
  __shared__ unsigned long long tile[256];
  int rank = 0;
  for (int t0 = 0; t0 < C; t0 += 256) {
    __syncthreads();
    int j = t0 + t;
    tile[t] = (j < C) ? cb[j] : 0ull;
    __syncthreads();
#pragma unroll 16
    for (int jj = 0; jj < 256; ++jj)
      rank += (tile[jj] > Ki) ? 1 : 0;
  }
  if (i < C && rank < PREN) {
    unsigned orig = ~(unsigned)(Ki & 0xffffffffull);
    float4 bb = *(const float4*)(boxes + ((size_t)n * NANCH + orig) * 4);
    *(float4*)(sboxes + ((size_t)n * PREN + rank) * 4) = bb;
  }
}

// ------------------ suppression bit-matrix (IoU > 0.7) --------------------
__global__ __launch_bounds__(256) void iou_kernel(
    const float* __restrict__ sboxes, unsigned long long* __restrict__ sup) {
#pragma clang fp contract(off)
  int n = blockIdx.y, i = blockIdx.x;
  const float* B = sboxes + (size_t)n * PREN * 4;
  float4 bi = *(const float4*)(B + (size_t)i * 4);
  float area_i = (bi.z - bi.x) * (bi.w - bi.y);
  int lane = threadIdx.x & 63, wv = threadIdx.x >> 6;
  unsigned long long* row = sup + ((size_t)n * PREN + i) * 64;
  for (int w0 = wv; w0 < 64; w0 += 4) {
    int j = w0 * 64 + lane;
    bool p = false;
    if (j < PREN) {
      float4 bj = *(const float4*)(B + (size_t)j * 4);
      float area_j = (bj.z - bj.x) * (bj.w - bj.y);
      float x1 = fmaxf(bi.x, bj.x), y1 = fmaxf(bi.y, bj.y);
      float x2 = fminf(bi.z, bj.z), y2 = fminf(bi.w, bj.w);
      float inter = fmaxf(x2 - x1, 0.f) * fmaxf(y2 - y1, 0.f);
      float iou = inter / (area_i + area_j - inter + 1e-9f);
      p = iou > 0.7f;
    }
    unsigned long long m = __ballot(p);
    if (lane == 0) row[w0] = m;
  }
}

// -------- word-wise greedy sweep (1 wave/image) + emit 300 rois -----------
__global__ __launch_bounds__(64) void nms_kernel(
    const unsigned long long* __restrict__ sup, const float* __restrict__ sboxes,
    float* __restrict__ rois, float* __restrict__ ridx) {
  int n = blockIdx.x;
  int lane = threadIdx.x;
  const unsigned long long* S = sup + (size_t)n * PREN * 64;
  unsigned long long buf[64];
#pragma unroll
  for (int bq = 0; bq < 64; ++bq) buf[bq] = S[(size_t)bq * 64 + lane];
  unsigned long long keep = (lane < 46) ? ~0ull
                          : (lane == 46 ? ((1ull << 56) - 1ull) : 0ull);  // 3000 bits
  for (int w = 0; w < 47; ++w) {
    unsigned long long kw = __shfl(keep, w);
    unsigned long long gtmask = (lane > w) ? ~0ull : 0ull;
#pragma unroll
    for (int bq = 0; bq < 64; ++bq) {
      const int i = w * 64 + bq;
      unsigned long long r = buf[bq];
      if (i + 64 < PREN) buf[bq] = S[(size_t)(i + 64) * 64 + lane];
      unsigned long long rw = __shfl(r, w);
      unsigned long long amask = ((kw >> bq) & 1ull) ? ~0ull : 0ull;
      const unsigned long long fmask = (bq == 63) ? 0ull : ~((2ull << bq) - 1ull);
      kw &= ~(rw & fmask & amask);
      keep &= ~(r & gtmask & amask);
    }
    keep = (lane == w) ? kw : keep;
  }
  int cnt = __popcll(keep);
  int scn = cnt;
  for (int d = 1; d < 64; d <<= 1) {
    int v = __shfl_up(scn, d);
    if (lane >= d) scn += v;
  }
  int excl = scn - cnt;
  int total = __shfl(scn, 63);
  const float* SB = sboxes + (size_t)n * PREN * 4;
  unsigned long long kk = keep;
  int p = excl;
  while (kk) {
    int bpos = __ffsll(kk) - 1;
    kk &= kk - 1ull;
    if (p < POSTN) {
      float4 bb = *(const float4*)(SB + (size_t)(lane * 64 + bpos) * 4);
      *(float4*)(rois + ((size_t)n * POSTN + p) * 4) = bb;
    }
    ++p;
  }
  if (lane == 0) {
    float4 b0 = *(const float4*)SB;
    for (int q = total; q < POSTN; ++q)
      *(float4*)(rois + ((size_t)n * POSTN + q) * 4) = b0;
  }
  for (int q = lane; q < POSTN; q += 64) ridx[n * POSTN + q] = (float)n;
}

extern "C" void kernel_launch(void* const* d_in, const int* in_sizes, int n_in,
                              void* d_out, int out_size, void* d_ws, size_t ws_size,
                              hipStream_t stream) {
  const float* x       = (const float*)d_in[0];
  const float* w_conv  = (const float*)d_in[1];
  const float* b_conv  = (const float*)d_in[2];
  const float* w_score = (const float*)d_in[3];
  const float* b_score = (const float*)d_in[4];
  const float* w_loc   = (const float*)d_in[5];
  const float* b_loc   = (const float*)d_in[6];
  const int*   img_h   = (const int*)d_in[7];
  const int*   img_w   = (const int*)d_in[8];

  float* out        = (float*)d_out;
  float* out_locs   = out;                 // (4,36864,4)  589824
  float* out_scores = out + 589824;        // (4,36864,2)  294912
  float* out_rois   = out + 884736;        // (4,300,4)      4800
  float* out_ridx   = out + 889536;        // (4,300)        1200
  float* out_anchor = out + 890736;        // (1,36864,4)  147456

  // ws: feat2 33.55MB | region A: w4 9.44MB (dead after conv3) aliased by
  // boxes/keys/sboxes/sup (9.28MB) | hist 1MB + cnt | cand 1.18MB
  float* feat2 = (float*)d_ws;                            // 8388608 f32
  float* A     = feat2 + (size_t)8388608;
  float* w4    = A;                                       // 2359296 f32
  float* boxes = A;                                       // 589824 f32
  unsigned* keys = (unsigned*)(boxes + 589824);           // 147456 u32
  float* sboxes  = (float*)(keys + 147456);               // 48000 f32
  unsigned long long* sup = (unsigned long long*)(sboxes + 48000); // 768000 u64
  unsigned* hist = (unsigned*)(A + 2359296);              // 262144 u32 (transposed)
  unsigned* cnt  = hist + 262148;                         // 4 u32 (zeroed in reshape)
  unsigned long long* cand = (unsigned long long*)(hist + 262160); // 147456 u64

  reshape_w_kernel<<<9216, 256, 0, stream>>>(w_conv, w4, hist);
  conv3_kernel<<<dim3(16, 16, 4), 256, 0, stream>>>(x, w4, b_conv, feat2);
  conv1_decode_kernel<<<dim3(64, 4, 2), 256, 0, stream>>>(
      feat2, w_loc, b_loc, w_score, b_score, img_h, img_w,
      out_locs, out_scores, boxes, keys, hist, out_anchor);
  compact_kernel<<<576, 256, 0, stream>>>(keys, hist, cnt, cand);
  rank2_kernel<<<dim3(144, 4), 256, 0, stream>>>(cand, cnt, boxes, sboxes);
  iou_kernel<<<dim3(PREN, 4), 256, 0, stream>>>(sboxes, sup);
  nms_kernel<<<4, 64, 0, stream>>>(sup, sboxes, out_rois, out_ridx);
}